// Round 2
// baseline (628.728 us; speedup 1.0000x reference)
//
#include <hip/hip_runtime.h>
#include <hip/hip_bf16.h>
#include <stdint.h>

typedef unsigned short ushort_t;
typedef __bf16 bf16x8 __attribute__((ext_vector_type(8)));
typedef float f32x16 __attribute__((ext_vector_type(16)));

#define BM 128
#define BN 128
#define BK 64   // 16 KB per tile; XOR-swizzled 16B chunks

// ---------- helpers ----------
__device__ inline float b2f(ushort_t u) {
    unsigned int x = ((unsigned int)u) << 16;
    float f; __builtin_memcpy(&f, &x, 4); return f;
}
__device__ inline ushort_t f2b(float f) {
    unsigned int x; __builtin_memcpy(&x, &f, 4);
    unsigned int r = (x + 0x7FFFu + ((x >> 16) & 1u)) >> 16;
    return (ushort_t)r;
}
__device__ inline void stage16(const ushort_t* g, ushort_t* s) {
    __builtin_amdgcn_global_load_lds((const __attribute__((address_space(1))) void*)g,
                                     (__attribute__((address_space(3))) void*)s, 16, 0, 0);
}
// swizzle position function: folds row bits 3-4 so stride-8 lane groups (HW b128
// conflict granularity; inferred R5/R6 counter A/B) never exceed 2-way.
__device__ inline int swz(int r) { return (r & 7) ^ ((r >> 3) & 3); }
// stage one 128x64 bf16 tile; LDS slot e (row e>>3, pos e&7) holds global chunk (e&7)^swz(row)
__device__ inline void stage_tile(const ushort_t* G, int ld, int k0, ushort_t* S, int tid) {
#pragma unroll
    for (int t = 0; t < 4; ++t) {
        int e = tid + t * 256;
        int row = e >> 3;
        int sw = ((e & 7) ^ swz(row)) * 8;
        stage16(G + (long long)row * ld + k0 + sw, &S[e * 8]);
    }
}
__device__ inline bf16x8 ldfrag(const ushort_t* S, int r, int c) {
    return *(const bf16x8*)&S[r * BK + ((c ^ swz(r)) * 8)];
}
// XCD-aware tile decode for 128^2 kernels (B-resident mapping; good when B is small
// relative to A re-reads, e.g. k_gemm_nt).
__device__ inline void tile_decode(int& m0, int& n0) {
    const int nx = gridDim.x;
    int lin = blockIdx.y * nx + blockIdx.x;
    if ((nx & 7) == 0) {
        int q = nx >> 3;
        int k = lin & 7, s = lin >> 3;
        n0 = (k * q + s % q) * BN;
        m0 = (s / q) * BM;
    } else {
        m0 = blockIdx.y * BM;
        n0 = blockIdx.x * BN;
    }
}

// ==================== 256-wide pipelined GEMM cores ====================
// Counted-vmcnt schedule (loads never drained to 0 in steady state); K-tile (64)
// split into two contiguous 16KB-region K-halves (global_load_lds linear dest);
// 2-bit XOR swizzle keeps ds_read_b128 at <=2-way bank aliasing (free, m136).

#define SBAR() __builtin_amdgcn_sched_barrier(0)
#define BARRIER() do { SBAR(); __builtin_amdgcn_s_barrier(); SBAR(); } while (0)
#define WAITV(N) asm volatile("s_waitcnt vmcnt(" #N ")" ::: "memory")

__device__ inline int sw2(int r) { return ((r) & 3) ^ ((r >> 3) & 3); }

// stage K-half h (cols 32h..32h+31) of a 256-row tile (2 loads/thread).
// slot s=(r*4+q) -> LDS half region Sbuf + h*8192; slot holds chunk 4h + (q^sw2(r)).
__device__ inline void stage_half(const ushort_t* G, int ldg, int kElem,
                                  ushort_t* Sbuf, int h, int tid) {
#pragma unroll
    for (int i2 = 0; i2 < 2; ++i2) {
        int s = tid + i2 * 512;
        int r = s >> 2, q = s & 3;
        int c = 4 * h + (q ^ sw2(r));
        stage16(G + (long long)r * ldg + kElem + c * 8, Sbuf + h * 8192 + s * 8);
    }
}
// stage K-half h of a 128-row tile (1 load/thread); half region stride 4096 ushorts.
__device__ inline void stage_halfA(const ushort_t* G, int ldg,
                                   ushort_t* Sbuf, int h, int tid) {
    int r = tid >> 2, q = tid & 3;
    int c = 4 * h + (q ^ sw2(r));
    stage16(G + (long long)r * ldg + c * 8, Sbuf + h * 4096 + tid * 8);
}
// read the 8-bf16 fragment (row r, K-chunk c in 0..7); hs = ushorts per half region
__device__ inline bf16x8 ldfrag2(const ushort_t* Sbuf, int r, int c, int hs) {
    int h = c >> 2;
    int lp = (c ^ sw2(r)) & 3;
    return *(const bf16x8*)&Sbuf[h * hs + r * 32 + lp * 8];
}

// ---- 256x256 core (8 waves of 128x64) -------------------------------------
template <int KS0, int MI0, bool LB>
__device__ __forceinline__ void phase_load(const ushort_t* cA, const ushort_t* cB,
                                           int wr, int wc, int l32, int hl,
                                           bf16x8 af_[2][2], bf16x8 bfr_[2][2]) {
#pragma unroll
    for (int k2 = 0; k2 < 2; ++k2) {
#pragma unroll
        for (int m2 = 0; m2 < 2; ++m2)
            af_[m2][k2] = ldfrag2(cA, wr * 128 + (MI0 + m2) * 32 + l32,
                                  (KS0 + k2) * 2 + hl, 8192);
        if (LB) {
#pragma unroll
            for (int n2 = 0; n2 < 2; ++n2)
                bfr_[n2][k2] = ldfrag2(cB, wc * 64 + n2 * 32 + l32,
                                       (KS0 + k2) * 2 + hl, 8192);
        }
    }
}
template <int KS0, int MI0>
__device__ __forceinline__ void phase_mfma(bf16x8 af_[2][2], bf16x8 bfr_[2][2],
                                           f32x16 (&acc)[4][2]) {
#pragma unroll
    for (int k2 = 0; k2 < 2; ++k2)
#pragma unroll
        for (int m2 = 0; m2 < 2; ++m2)
#pragma unroll
            for (int n2 = 0; n2 < 2; ++n2)
                acc[MI0 + m2][n2] = __builtin_amdgcn_mfma_f32_32x32x16_bf16(
                    af_[m2][k2], bfr_[n2][k2], acc[MI0 + m2][n2], 0, 0, 0);
}

// requires K % 64 == 0 and K >= 128
__device__ __forceinline__ void gemm256_core(const ushort_t* __restrict__ Ag, int lda,
                                             const ushort_t* __restrict__ Bg, int ldb,
                                             int K, ushort_t* smem, int tid,
                                             int wr, int wc, int l32, int hl,
                                             f32x16 (&acc)[4][2]) {
    ushort_t* A0s = smem;
    ushort_t* A1s = smem + 16384;
    ushort_t* B0s = smem + 32768;
    ushort_t* B1s = smem + 49152;
    const int NT = K >> 6;

    // prologue: A0(0),B0(0),A1(0),B1(0),A0(1),B0(1) then wait for A0,B0(0)
    stage_half(Ag, lda, 0, A0s, 0, tid);
    stage_half(Bg, ldb, 0, B0s, 0, tid);
    stage_half(Ag, lda, 0, A0s, 1, tid);
    stage_half(Bg, ldb, 0, B0s, 1, tid);
    stage_half(Ag, lda, 64, A1s, 0, tid);
    stage_half(Bg, ldb, 64, B1s, 0, tid);
    WAITV(8);
    BARRIER();

    for (int kt = 0; kt < NT; ++kt) {
        ushort_t* cA = (kt & 1) ? A1s : A0s;
        ushort_t* cB = (kt & 1) ? B1s : B0s;
        ushort_t* nA = (kt & 1) ? A0s : A1s;
        ushort_t* nB = (kt & 1) ? B0s : B1s;
        const bool h1 = (kt + 1 < NT), h2 = (kt + 2 < NT);
        const int kE1 = (kt + 1) << 6, kE2 = (kt + 2) << 6;
        bf16x8 af_[2][2], bfr_[2][2];
        // ---- P1: issue A1(kt+1); compute (ks 0-1, mi 0-1)
        if (h1) stage_half(Ag, lda, kE1, nA, 1, tid);
        phase_load<0, 0, true>(cA, cB, wr, wc, l32, hl, af_, bfr_);
        BARRIER();
        __builtin_amdgcn_s_setprio(1);
        phase_mfma<0, 0>(af_, bfr_, acc);
        __builtin_amdgcn_s_setprio(0);
        BARRIER();
        // ---- P2: issue B1(kt+1); compute (ks 0-1, mi 2-3); wait for A1,B1(kt)
        if (h1) stage_half(Bg, ldb, kE1, nB, 1, tid);
        phase_load<0, 2, false>(cA, cB, wr, wc, l32, hl, af_, bfr_);
        BARRIER();
        __builtin_amdgcn_s_setprio(1);
        phase_mfma<0, 2>(af_, bfr_, acc);
        __builtin_amdgcn_s_setprio(0);
        if (h1) { WAITV(8); } else { WAITV(0); }
        BARRIER();
        // ---- P3: issue A0(kt+2); compute (ks 2-3, mi 0-1)
        if (h2) stage_half(Ag, lda, kE2, cA, 0, tid);
        phase_load<2, 0, true>(cA, cB, wr, wc, l32, hl, af_, bfr_);
        BARRIER();
        __builtin_amdgcn_s_setprio(1);
        phase_mfma<2, 0>(af_, bfr_, acc);
        __builtin_amdgcn_s_setprio(0);
        BARRIER();
        // ---- P4: issue B0(kt+2); compute (ks 2-3, mi 2-3); wait for A0,B0(kt+1)
        if (h2) stage_half(Bg, ldb, kE2, cB, 0, tid);
        phase_load<2, 2, false>(cA, cB, wr, wc, l32, hl, af_, bfr_);
        BARRIER();
        __builtin_amdgcn_s_setprio(1);
        phase_mfma<2, 2>(af_, bfr_, acc);
        __builtin_amdgcn_s_setprio(0);
        if (h1) { if (h2) { WAITV(8); } else { WAITV(4); } }
        BARRIER();
    }
}

// ---- 256^2 fused gate_up GEMM + in-register SiLU (weights row-PERMUTED:
// permuted row 64q+s = gate row 32q+s (s<32) else up row 32q+s-32, so
// acc[mi][0]=gate, acc[mi][1]=up for the SAME h column). grid (32,32), 512 thr.
__global__ __launch_bounds__(512, 2)
void k_gemm256_silu(const ushort_t* __restrict__ A, const ushort_t* __restrict__ Bp,
                    ushort_t* __restrict__ H) {
    extern __shared__ __attribute__((aligned(16))) ushort_t smem2[];
    const int tid = threadIdx.x;
    const int lane = tid & 63, l32 = lane & 31, hl = lane >> 5;
    const int wv = tid >> 6, wr = wv >> 2, wc = wv & 3;
    // XCD-aware 256-tile decode: XCD k owns 4 n-tiles, sweeps m (nwg=1024, %8==0)
    int lin = blockIdx.y * 32 + blockIdx.x;
    int k8 = lin & 7, s = lin >> 3;
    int n0 = (k8 * 4 + (s & 3)) * 256;
    int m0 = (s >> 2) * 256;
    const ushort_t* Ag = A + (long long)m0 * 1024;
    const ushort_t* Bg = Bp + (long long)n0 * 1024;
    f32x16 acc[4][2];
#pragma unroll
    for (int i = 0; i < 4; ++i) { acc[i][0] = (f32x16)(0.f); acc[i][1] = (f32x16)(0.f); }
    gemm256_core(Ag, 1024, Bg, 1024, 1024, smem2, tid, wr, wc, l32, hl, acc);
    const int hc = (n0 >> 1) + wc * 32 + l32;
#pragma unroll
    for (int mi = 0; mi < 4; ++mi)
#pragma unroll
        for (int reg = 0; reg < 16; ++reg) {
            int row = m0 + wr * 128 + mi * 32 + (reg & 3) + 8 * (reg >> 2) + 4 * hl;
            float g = acc[mi][0][reg], u = acc[mi][1][reg];
            float sg = g / (1.f + __expf(-g));
            H[(long long)row * 4096 + hc] = f2b(sg * u);
        }
}

// ---- 256^2 triangular P GEMM: one block per (b,i,j) pair (exactly one 256^2
// tile). Bijective XCD remap: XCD x gets 30 consecutive pairIdx -> same-i runs
// share an XCD's L2 (h_i stays hot).
__global__ __launch_bounds__(512, 2)
void k_gemm256_tri(const ushort_t* __restrict__ Hh, ushort_t* __restrict__ P) {
    extern __shared__ __attribute__((aligned(16))) ushort_t smem2[];
    const int tid = threadIdx.x;
    const int lane = tid & 63, l32 = lane & 31, hl = lane >> 5;
    const int wv = tid >> 6, wr = wv >> 2, wc = wv & 3;
    int pairIdx = (blockIdx.x & 7) * 30 + (blockIdx.x >> 3);   // 240 = 8*30
    const int bb = pairIdx / 120;
    int p = pairIdx % 120;
    int i = 1, rem = p;
    while (rem >= i) { rem -= i; ++i; }
    const int j = rem;
    const ushort_t* Ag = Hh + (long long)bb * 4096 * 4096 + (long long)(i * 256) * 4096;
    const ushort_t* Bg = Hh + (long long)bb * 4096 * 4096 + (long long)(j * 256) * 4096;
    f32x16 acc[4][2];
#pragma unroll
    for (int a = 0; a < 4; ++a) { acc[a][0] = (f32x16)(0.f); acc[a][1] = (f32x16)(0.f); }
    gemm256_core(Ag, 4096, Bg, 4096, 4096, smem2, tid, wr, wc, l32, hl, acc);
    ushort_t* Pp = P + (long long)bb * 4096 * 4096;
#pragma unroll
    for (int mi = 0; mi < 4; ++mi)
#pragma unroll
        for (int nj = 0; nj < 2; ++nj) {
            int col = j * 256 + wc * 64 + nj * 32 + l32;
#pragma unroll
            for (int reg = 0; reg < 16; ++reg) {
                int row = i * 256 + wr * 128 + mi * 32 + (reg & 3) + 8 * (reg >> 2) + 4 * hl;
                Pp[(long long)row * 4096 + col] = f2b(acc[mi][nj][reg]);
            }
        }
}

// ==================== fused output GEMM, pipelined 128x256 ====================
// out[b,ii] = [h_ii | P_ii,0:ii*C] @ [wdown | tpT]^T, K = 4096 + ii*256.
// 256 blocks (512 thr, 8 waves of 64x64, 96 KiB LDS -> 1 block/CU, all resident).
// A-resident XCD decode: XCD x owns z in {4x..4x+3} x all 8 (m,n)-tiles -> each
// z's A rows (h+P) fetched ~once per XCD; wdown/tpT stream in loose k-sync
// across the 4 co-resident z's. 2 phases/K-tile, counted vmcnt (6 loads/K-tile:
// A halves 1 load, B halves 2 loads).
__device__ __forceinline__ void oload_ks(const ushort_t* cA, const ushort_t* cB,
                                         int ks0, int wr, int wc, int l32, int hl,
                                         bf16x8 af_[2][2], bf16x8 bf_[2][2]) {
#pragma unroll
    for (int k2 = 0; k2 < 2; ++k2) {
        int c = (ks0 + k2) * 2 + hl;
#pragma unroll
        for (int m2 = 0; m2 < 2; ++m2)
            af_[m2][k2] = ldfrag2(cA, wr * 64 + m2 * 32 + l32, c, 4096);
#pragma unroll
        for (int n2 = 0; n2 < 2; ++n2)
            bf_[n2][k2] = ldfrag2(cB, wc * 64 + n2 * 32 + l32, c, 8192);
    }
}
__device__ __forceinline__ void omfma(bf16x8 af_[2][2], bf16x8 bf_[2][2],
                                      f32x16 (&acc)[2][2]) {
#pragma unroll
    for (int k2 = 0; k2 < 2; ++k2)
#pragma unroll
        for (int m2 = 0; m2 < 2; ++m2)
#pragma unroll
            for (int n2 = 0; n2 < 2; ++n2)
                acc[m2][n2] = __builtin_amdgcn_mfma_f32_32x32x16_bf16(
                    af_[m2][k2], bf_[n2][k2], acc[m2][n2], 0, 0, 0);
}

__global__ __launch_bounds__(512, 2)
void k_gemm256_out(const ushort_t* __restrict__ h, const ushort_t* __restrict__ wdown,
                   const ushort_t* __restrict__ P, const ushort_t* __restrict__ tpT,
                   float* __restrict__ out) {
    constexpr int T = 4096, D = 1024, F = 4096, C = 256, K1 = 4096;
    extern __shared__ __attribute__((aligned(16))) ushort_t smem2[];
    const int tid = threadIdx.x;
    const int lane = tid & 63, l32 = lane & 31, hl = lane >> 5;
    const int wv = tid >> 6, wr = wv >> 2, wc = wv & 3;   // wr 0..1, wc 0..3

    // A-resident XCD decode: physical bx -> XCD = bx&7 owns logical 32-chunk.
    const int bx = blockIdx.x;
    const int logical = (bx & 7) * 32 + (bx >> 3);        // 256 blocks
    const int z = logical >> 3, t = logical & 7;          // z 0..31
    const int bb = z >> 4, ii = z & 15;
    const int m0 = (t >> 2) * 128, n0 = (t & 3) * 256;
    const int K = K1 + ii * C;

    const ushort_t* hA = h + (long long)bb * T * F + (long long)(ii * C + m0) * F;
    const ushort_t* pA = P + (long long)bb * T * T + (long long)(ii * C + m0) * T;
    const ushort_t* wB = wdown + (long long)n0 * F;
    const ushort_t* tB = tpT + (long long)bb * D * T + (long long)n0 * T;

    ushort_t* A0s = smem2;              // 8192 ushorts each (16 KB)
    ushort_t* A1s = smem2 + 8192;
    ushort_t* B0s = smem2 + 16384;      // 16384 ushorts each (32 KB)
    ushort_t* B1s = smem2 + 32768;

    f32x16 acc[2][2];
#pragma unroll
    for (int a = 0; a < 2; ++a)
#pragma unroll
        for (int c = 0; c < 2; ++c) acc[a][c] = (f32x16)(0.f);

    auto srcA = [&](int kE) { return kE < K1 ? hA + kE : pA + (kE - K1); };
    auto srcB = [&](int kE) { return kE < K1 ? wB + kE : tB + (kE - K1); };

    const int NT = K >> 6;   // >= 64

    // prologue: A(0)h0,B(0)h0,A(0)h1,B(0)h1,A(1)h0,B(1)h0  (9 loads)
    stage_halfA(srcA(0), F, A0s, 0, tid);
    stage_half (srcB(0), F, 0, B0s, 0, tid);
    stage_halfA(srcA(0), F, A0s, 1, tid);
    stage_half (srcB(0), F, 0, B0s, 1, tid);
    stage_halfA(srcA(64), F, A1s, 0, tid);
    stage_half (srcB(64), F, 0, B1s, 0, tid);
    WAITV(6);
    BARRIER();

    for (int kt = 0; kt < NT; ++kt) {
        ushort_t* cA = (kt & 1) ? A1s : A0s;
        ushort_t* cB = (kt & 1) ? B1s : B0s;
        ushort_t* nA = (kt & 1) ? A0s : A1s;
        ushort_t* nB = (kt & 1) ? B0s : B1s;
        const bool h1 = (kt + 1 < NT), h2 = (kt + 2 < NT);
        const int kE1 = (kt + 1) << 6, kE2 = (kt + 2) << 6;
        bf16x8 af_[2][2], bf_[2][2];
        // ---- PH1: issue A(kt+1)h1 + B(kt+1)h1; compute ks 0-1; wait A/B(kt)h1
        if (h1) {
            stage_halfA(srcA(kE1), F, nA, 1, tid);
            stage_half (srcB(kE1), F, 0, nB, 1, tid);
        }
        oload_ks(cA, cB, 0, wr, wc, l32, hl, af_, bf_);
        BARRIER();
        __builtin_amdgcn_s_setprio(1);
        omfma(af_, bf_, acc);
        __builtin_amdgcn_s_setprio(0);
        if (h1) { WAITV(6); } else { WAITV(0); }
        BARRIER();
        // ---- PH2: issue A(kt+2)h0 + B(kt+2)h0; compute ks 2-3; wait A/B(kt+1)h0
        if (h2) {
            stage_halfA(srcA(kE2), F, cA, 0, tid);
            stage_half (srcB(kE2), F, 0, cB, 0, tid);
        }
        oload_ks(cA, cB, 2, wr, wc, l32, hl, af_, bf_);
        BARRIER();
        __builtin_amdgcn_s_setprio(1);
        omfma(af_, bf_, acc);
        __builtin_amdgcn_s_setprio(0);
        if (h2) { WAITV(6); } else { if (h1) { WAITV(3); } else { WAITV(0); } }
        BARRIER();
    }

    float* Op = out + (long long)bb * T * D + (long long)(ii * C) * D;
#pragma unroll
    for (int mi = 0; mi < 2; ++mi)
#pragma unroll
        for (int nj = 0; nj < 2; ++nj) {
            int col = n0 + wc * 64 + nj * 32 + l32;
#pragma unroll
            for (int reg = 0; reg < 16; ++reg) {
                int row = m0 + wr * 64 + mi * 32 + (reg & 3) + 8 * (reg >> 2) + 4 * hl;
                Op[(long long)row * D + col] = acc[mi][nj][reg];
            }
        }
}

// ---------- fused prep: fp32->bf16 converts (x|wgu|proj|wdown) + causal conv ----------
// permW: write wgu in the gate/up-interleaved row order for k_gemm256_silu.
__global__ void k_prep(const float* __restrict__ x, const float* __restrict__ wgu,
                       const float* __restrict__ proj, const float* __restrict__ wdown,
                       const float* __restrict__ tt, const float* __restrict__ cw,
                       const float* __restrict__ cb,
                       ushort_t* __restrict__ xb, ushort_t* __restrict__ gb,
                       ushort_t* __restrict__ pb, ushort_t* __restrict__ wb,
                       ushort_t* __restrict__ tb, int permW) {
    constexpr int T = 4096, D = 1024;
    int blk = blockIdx.x;
    if (blk < 21504) {
        // converts, float4-wide: x 2097152 | wgu 2097152 | proj 262144 | wdown 1048576 units
        int i = blk * 256 + threadIdx.x;
        const float* src; ushort_t* dst; int off; int dstoff;
        if (i < 2097152)      { src = x;     dst = xb; off = i; dstoff = off; }
        else if (i < 4194304) {
            src = wgu; dst = gb; off = i - 2097152;
            if (permW) {
                int r = off >> 8, cu = off & 255;
                int pr = (r < 4096) ? (((r >> 5) << 6) + (r & 31))
                                    : ((((r - 4096) >> 5) << 6) + 32 + ((r - 4096) & 31));
                dstoff = (pr << 8) + cu;
            } else dstoff = off;
        }
        else if (i < 4456448) { src = proj;  dst = pb; off = i - 4194304; dstoff = off; }
        else                  { src = wdown; dst = wb; off = i - 4456448; dstoff = off; }
        float4 v = ((const float4*)src)[off];
        ushort4 o; o.x = f2b(v.x); o.y = f2b(v.y); o.z = f2b(v.z); o.w = f2b(v.w);
        ((ushort4*)dst)[dstoff] = o;
    } else {
        // causal depthwise conv (K=5)
        int idx = (blk - 21504) * 256 + threadIdx.x;
        int d = idx % D;
        int t = (idx / D) % T;
        int b = idx / (D * T);
        float acc = cb[d];
#pragma unroll
        for (int k = 0; k < 5; ++k) {
            int ts = t - 4 + k;
            if (ts >= 0) acc += tt[(long long)b * T * D + (long long)ts * D + d] * cw[d * 5 + k];
        }
        tb[idx] = f2b(acc);
    }
}

// ---------- batched bf16 NT GEMM (bf16 out): C[m,n] = scale * sum_k A[m,k]*B[n,k] ----------
__global__ __launch_bounds__(256, 4)
void k_gemm_nt(const ushort_t* __restrict__ A, const ushort_t* __restrict__ B,
               ushort_t* __restrict__ C, int K, int lda, int ldb, int ldc,
               long long sAb, long long sBb, long long sCb, float scale) {
    __shared__ __attribute__((aligned(16))) ushort_t sA[BM * BK];
    __shared__ __attribute__((aligned(16))) ushort_t sB[BN * BK];

    int m0, n0;
    tile_decode(m0, n0);
    const int bb = blockIdx.z;
    const ushort_t* Ab = A + bb * sAb + (long long)m0 * lda;
    const ushort_t* Bb = B + bb * sBb + (long long)n0 * ldb;

    const int tid = threadIdx.x;
    const int lane = tid & 63, l32 = lane & 31, half = lane >> 5;
    const int wave = tid >> 6;
    const int wm = (wave >> 1) * 64, wn = (wave & 1) * 64;

    f32x16 acc[2][2];
#pragma unroll
    for (int i = 0; i < 2; ++i)
#pragma unroll
        for (int j = 0; j < 2; ++j) acc[i][j] = (f32x16)(0.f);

    for (int k0 = 0; k0 < K; k0 += BK) {
        __syncthreads();
        stage_tile(Ab, lda, k0, sA, tid);
        stage_tile(Bb, ldb, k0, sB, tid);
        __syncthreads();
#pragma unroll
        for (int ks = 0; ks < 4; ++ks) {
            bf16x8 af[2], bfr[2];
#pragma unroll
            for (int mi = 0; mi < 2; ++mi)
                af[mi] = ldfrag(sA, wm + mi * 32 + l32, ks * 2 + half);
#pragma unroll
            for (int nj = 0; nj < 2; ++nj)
                bfr[nj] = ldfrag(sB, wn + nj * 32 + l32, ks * 2 + half);
#pragma unroll
            for (int mi = 0; mi < 2; ++mi)
#pragma unroll
                for (int nj = 0; nj < 2; ++nj)
                    acc[mi][nj] = __builtin_amdgcn_mfma_f32_32x32x16_bf16(af[mi], bfr[nj], acc[mi][nj], 0, 0, 0);
        }
    }

    ushort_t* Cp = C + bb * sCb;
#pragma unroll
    for (int mi = 0; mi < 2; ++mi)
#pragma unroll
        for (int nj = 0; nj < 2; ++nj) {
            int col = n0 + wn + nj * 32 + l32;
#pragma unroll
            for (int reg = 0; reg < 16; ++reg) {
                int row = m0 + wm + mi * 32 + (reg & 3) + 8 * (reg >> 2) + 4 * half;
                Cp[(long long)row * ldc + col] = f2b(acc[mi][nj][reg] * scale);
            }
        }
}

// ---------- fallback fused gate_up GEMM + SiLU (unpermuted weights) ----------
__global__ __launch_bounds__(256)
void k_gemm_silu(const ushort_t* __restrict__ A, const ushort_t* __restrict__ Bg,
                 const ushort_t* __restrict__ Bu, ushort_t* __restrict__ H,
                 int K, int lda, int ldb, int ldh) {
    __shared__ __attribute__((aligned(16))) ushort_t sA[BM * BK];
    __shared__ __attribute__((aligned(16))) ushort_t sBg[BN * BK];
    __shared__ __attribute__((aligned(16))) ushort_t sBu[BN * BK];

    int m0, n0;
    tile_decode(m0, n0);
    const ushort_t* Ab = A + (long long)m0 * lda;
    const ushort_t* Bgb = Bg + (long long)n0 * ldb;
    const ushort_t* Bub = Bu + (long long)n0 * ldb;

    const int tid = threadIdx.x;
    const int lane = tid & 63, l32 = lane & 31, half = lane >> 5;
    const int wave = tid >> 6;
    const int wm = (wave >> 1) * 64, wn = (wave & 1) * 64;

    f32x16 ag[2][2], au[2][2];
#pragma unroll
    for (int i = 0; i < 2; ++i)
#pragma unroll
        for (int j = 0; j < 2; ++j) { ag[i][j] = (f32x16)(0.f); au[i][j] = (f32x16)(0.f); }

    for (int k0 = 0; k0 < K; k0 += BK) {
        __syncthreads();
        stage_tile(Ab, lda, k0, sA, tid);
        stage_tile(Bgb, ldb, k0, sBg, tid);
        stage_tile(Bub, ldb, k0, sBu, tid);
        __syncthreads();
#pragma unroll
        for (int ks = 0; ks < 4; ++ks) {
            bf16x8 af[2], bg[2], bu[2];
#pragma unroll
            for (int mi = 0; mi < 2; ++mi)
                af[mi] = ldfrag(sA, wm + mi * 32 + l32, ks * 2 + half);
#pragma unroll
            for (int nj = 0; nj < 2; ++nj) {
                bg[nj] = ldfrag(sBg, wn + nj * 32 + l32, ks * 2 + half);
                bu[nj] = ldfrag(sBu, wn + nj * 32 + l32, ks * 2 + half);
            }
#pragma unroll
            for (int mi = 0; mi < 2; ++mi)
#pragma unroll
                for (int nj = 0; nj < 2; ++nj) {
                    ag[mi][nj] = __builtin_amdgcn_mfma_f32_32x32x16_bf16(af[mi], bg[nj], ag[mi][nj], 0, 0, 0);
                    au[mi][nj] = __builtin_amdgcn_mfma_f32_32x32x16_bf16(af[mi], bu[nj], au[mi][nj], 0, 0, 0);
                }
        }
    }

#pragma unroll
    for (int mi = 0; mi < 2; ++mi)
#pragma unroll
        for (int nj = 0; nj < 2; ++nj) {
            int col = n0 + wn + nj * 32 + l32;
#pragma unroll
            for (int reg = 0; reg < 16; ++reg) {
                int row = m0 + wm + mi * 32 + (reg & 3) + 8 * (reg >> 2) + 4 * half;
                float g = ag[mi][nj][reg], u = au[mi][nj][reg];
                float s = g / (1.f + __expf(-g));
                H[(long long)row * ldh + col] = f2b(s * u);
            }
        }
}

// ---------- fallback triangular P GEMM (128^2 tiles) ----------
__global__ __launch_bounds__(256, 4)
void k_gemm_tri(const ushort_t* __restrict__ H, ushort_t* __restrict__ P,
                int K, int ldh, int ldp, long long sHb, long long sPb) {
    __shared__ __attribute__((aligned(16))) ushort_t sA[BM * BK];
    __shared__ __attribute__((aligned(16))) ushort_t sB[BN * BK];

    const int lin = blockIdx.x;
    const int g = lin >> 5, w = lin & 31;
    const int xk = w & 7, t = w >> 3;
    int pairIdx = g * 8 + xk;            // 0..239
    const int bb = pairIdx / 120;
    int p = pairIdx % 120;
    int i = 1, rem = p;
    while (rem >= i) { rem -= i; ++i; }
    const int j = rem;
    const int m0 = (t >> 1) * BM, n0 = (t & 1) * BN;

    const ushort_t* Ab = H + bb * sHb + (long long)(i * 256 + m0) * ldh;
    const ushort_t* Bb = H + bb * sHb + (long long)(j * 256 + n0) * ldh;

    const int tid = threadIdx.x;
    const int lane = tid & 63, l32 = lane & 31, half = lane >> 5;
    const int wave = tid >> 6;
    const int wm = (wave >> 1) * 64, wn = (wave & 1) * 64;

    f32x16 acc[2][2];
#pragma unroll
    for (int a = 0; a < 2; ++a)
#pragma unroll
        for (int c = 0; c < 2; ++c) acc[a][c] = (f32x16)(0.f);

    for (int k0 = 0; k0 < K; k0 += BK) {
        __syncthreads();
        stage_tile(Ab, ldh, k0, sA, tid);
        stage_tile(Bb, ldh, k0, sB, tid);
        __syncthreads();
#pragma unroll
        for (int ks = 0; ks < 4; ++ks) {
            bf16x8 af[2], bfr[2];
#pragma unroll
            for (int mi = 0; mi < 2; ++mi)
                af[mi] = ldfrag(sA, wm + mi * 32 + l32, ks * 2 + half);
#pragma unroll
            for (int nj = 0; nj < 2; ++nj)
                bfr[nj] = ldfrag(sB, wn + nj * 32 + l32, ks * 2 + half);
#pragma unroll
            for (int mi = 0; mi < 2; ++mi)
#pragma unroll
                for (int nj = 0; nj < 2; ++nj)
                    acc[mi][nj] = __builtin_amdgcn_mfma_f32_32x32x16_bf16(af[mi], bfr[nj], acc[mi][nj], 0, 0, 0);
        }
    }

    ushort_t* Pp = P + bb * sPb;
#pragma unroll
    for (int mi = 0; mi < 2; ++mi)
#pragma unroll
        for (int nj = 0; nj < 2; ++nj) {
            int col = j * 256 + n0 + wn + nj * 32 + l32;
#pragma unroll
            for (int reg = 0; reg < 16; ++reg) {
                int row = i * 256 + m0 + wm + mi * 32 + (reg & 3) + 8 * (reg >> 2) + 4 * half;
                Pp[(long long)row * ldp + col] = f2b(acc[mi][nj][reg]);
            }
        }
}

// ---------- fallback fused output GEMM (128^2) ----------
__global__ __launch_bounds__(256, 4)
void k_gemm_out(const ushort_t* __restrict__ h, const ushort_t* __restrict__ wdown,
                const ushort_t* __restrict__ P, const ushort_t* __restrict__ tpT,
                float* __restrict__ out) {
    constexpr int T = 4096, D = 1024, F = 4096, C = 256, K1 = 4096;
    __shared__ __attribute__((aligned(16))) ushort_t sA[BM * BK];
    __shared__ __attribute__((aligned(16))) ushort_t sB[BN * BK];

    const int z = blockIdx.z, bb = z >> 4, ii = z & 15;
    const int K2 = ii * C;
    int m0, n0;
    tile_decode(m0, n0);

    const ushort_t* A1 = h + (long long)bb * T * F + (long long)(ii * C + m0) * F;
    const ushort_t* B1 = wdown + (long long)n0 * F;
    const ushort_t* A2 = P + (long long)bb * T * T + (long long)(ii * C + m0) * T;
    const ushort_t* B2 = tpT + (long long)bb * D * T + (long long)n0 * T;

    const int tid = threadIdx.x;
    const int lane = tid & 63, l32 = lane & 31, half = lane >> 5;
    const int wave = tid >> 6;
    const int wm = (wave >> 1) * 64, wn = (wave & 1) * 64;

    f32x16 acc[2][2];
#pragma unroll
    for (int i = 0; i < 2; ++i)
#pragma unroll
        for (int j = 0; j < 2; ++j) acc[i][j] = (f32x16)(0.f);

    const int K = K1 + K2;
    for (int k0 = 0; k0 < K; k0 += BK) {
        const ushort_t* As = (k0 < K1) ? A1 + k0 : A2 + (k0 - K1);
        const ushort_t* Bs = (k0 < K1) ? B1 + k0 : B2 + (k0 - K1);
        __syncthreads();
        stage_tile(As, 4096, 0, sA, tid);
        stage_tile(Bs, 4096, 0, sB, tid);
        __syncthreads();
#pragma unroll
        for (int ks = 0; ks < 4; ++ks) {
            bf16x8 af[2], bfr[2];
#pragma unroll
            for (int mi = 0; mi < 2; ++mi)
                af[mi] = ldfrag(sA, wm + mi * 32 + l32, ks * 2 + half);
#pragma unroll
            for (int nj = 0; nj < 2; ++nj)
                bfr[nj] = ldfrag(sB, wn + nj * 32 + l32, ks * 2 + half);
#pragma unroll
            for (int mi = 0; mi < 2; ++mi)
#pragma unroll
                for (int nj = 0; nj < 2; ++nj)
                    acc[mi][nj] = __builtin_amdgcn_mfma_f32_32x32x16_bf16(af[mi], bfr[nj], acc[mi][nj], 0, 0, 0);
        }
    }

    float* Op = out + (long long)bb * T * D + (long long)ii * C * D;
#pragma unroll
    for (int mi = 0; mi < 2; ++mi)
#pragma unroll
        for (int nj = 0; nj < 2; ++nj) {
            int col = n0 + wn + nj * 32 + l32;
#pragma unroll
            for (int reg = 0; reg < 16; ++reg) {
                int row = m0 + wm + mi * 32 + (reg & 3) + 8 * (reg >> 2) + 4 * half;
                Op[(long long)row * D + col] = acc[mi][nj][reg];
            }
        }
}

// ---------- launch ----------
static int g_big = -1;

extern "C" void kernel_launch(void* const* d_in, const int* in_sizes, int n_in,
                              void* d_out, int out_size, void* d_ws, size_t ws_size,
                              hipStream_t stream) {
    const float* x         = (const float*)d_in[0];
    const float* ttt_tgt   = (const float*)d_in[1];
    const float* w_gate_up = (const float*)d_in[2];
    const float* w_down    = (const float*)d_in[3];
    const float* ttt_proj  = (const float*)d_in[4];
    const float* conv_w    = (const float*)d_in[5];
    const float* conv_b    = (const float*)d_in[6];
    float* out = (float*)d_out;
    (void)in_sizes; (void)n_in; (void)out_size; (void)ws_size;

    constexpr int Bb = 2, T = 4096, D = 1024, F = 4096, C = 256;
    constexpr float LR = 0.01f;

    // one-time: opt in to big dynamic LDS for the pipelined kernels; if the
    // runtime refuses, fall back to the 128^2 path (status-quo performance).
    if (g_big < 0) {
        hipError_t e1 = hipFuncSetAttribute((const void*)k_gemm256_silu,
                                            hipFuncAttributeMaxDynamicSharedMemorySize, 131072);
        hipError_t e2 = hipFuncSetAttribute((const void*)k_gemm256_tri,
                                            hipFuncAttributeMaxDynamicSharedMemorySize, 131072);
        hipError_t e3 = hipFuncSetAttribute((const void*)k_gemm256_out,
                                            hipFuncAttributeMaxDynamicSharedMemorySize, 98304);
        g_big = (e1 == hipSuccess && e2 == hipSuccess && e3 == hipSuccess) ? 1 : 0;
    }

    // workspace (154 MB):
    //   [0,64M): x_bf(16M) | wgu_bf(16M) | t_bf(16M) | scratch  -> later aliased by P (B,T,T) bf16
    //   [64M..): proj_bf 2M | wdown_bf 8M | tpT 16M | h 64M
    char* ws = (char*)d_ws;
    ushort_t* x_bf     = (ushort_t*)(ws);
    ushort_t* wgu_bf   = (ushort_t*)(ws + 16777216LL);
    ushort_t* t_bf     = (ushort_t*)(ws + 2 * 16777216LL);
    ushort_t* P        = (ushort_t*)(ws);
    ushort_t* proj_bf  = (ushort_t*)(ws + 67108864LL);
    ushort_t* wdown_bf = (ushort_t*)(ws + 67108864LL + 2097152LL);
    ushort_t* tpT      = (ushort_t*)(ws + 67108864LL + 2097152LL + 8388608LL);
    ushort_t* h        = (ushort_t*)(ws + 67108864LL + 2097152LL + 8388608LL + 16777216LL);

    // 1) fused prep: converts (+ optional gate/up row interleave) + causal conv
    k_prep<<<21504 + 32768, 256, 0, stream>>>(x, w_gate_up, ttt_proj, w_down,
                                              ttt_tgt, conv_w, conv_b,
                                              x_bf, wgu_bf, proj_bf, wdown_bf, t_bf, g_big);

    // 2) tpT[b] = LR * (proj @ t[b]^T) : M=D, N=T, K=D -> bf16 (B,D,T)
    k_gemm_nt<<<dim3(T / BN, D / BM, Bb), 256, 0, stream>>>(
        proj_bf, t_bf, tpT, D, D, D, T,
        0, (long long)T * D, (long long)D * T, LR);

    // 3) h = silu(x@Wg^T)*(x@Wu^T) : M=B*T=8192, N(permuted)=8192, K=1024
    if (g_big) {
        k_gemm256_silu<<<dim3(32, 32, 1), 512, 131072, stream>>>(x_bf, wgu_bf, h);
    } else {
        k_gemm_silu<<<dim3(F / BN, (Bb * T) / BM, 1), 256, 0, stream>>>(
            x_bf, wgu_bf, wgu_bf + (long long)F * D, h, D, D, D, F);
    }

    // 4) P lower chunk-blocks: P[b, i*C.., j*C..] = h_i h_j^T, j<i
    if (g_big) {
        k_gemm256_tri<<<dim3(240, 1, 1), 512, 131072, stream>>>(h, P);
    } else {
        k_gemm_tri<<<dim3(960, 1, 1), 256, 0, stream>>>(
            h, P, F, F, T, (long long)T * F, (long long)T * T);
    }

    // 5) out[b,i] = [h_i | P] @ [wdown | LR*tpT]^T  (variable K = 4096 + i*256)
    if (g_big) {
        k_gemm256_out<<<dim3(256, 1, 1), 512, 98304, stream>>>(h, wdown_bf, P, tpT, out);
    } else {
        k_gemm_out<<<dim3(D / BN, C / BM, Bb * 16), 256, 0, stream>>>(
            h, wdown_bf, P, tpT, out);
    }
}

// Round 3
// 614.965 us; speedup vs baseline: 1.0224x; 1.0224x over previous
//
#include <hip/hip_runtime.h>
#include <hip/hip_bf16.h>
#include <stdint.h>

typedef unsigned short ushort_t;
typedef __bf16 bf16x8 __attribute__((ext_vector_type(8)));
typedef float f32x16 __attribute__((ext_vector_type(16)));

#define BM 128
#define BN 128
#define BK 64   // 16 KB per tile; XOR-swizzled 16B chunks

// ---------- helpers ----------
__device__ inline float b2f(ushort_t u) {
    unsigned int x = ((unsigned int)u) << 16;
    float f; __builtin_memcpy(&f, &x, 4); return f;
}
__device__ inline ushort_t f2b(float f) {
    unsigned int x; __builtin_memcpy(&x, &f, 4);
    unsigned int r = (x + 0x7FFFu + ((x >> 16) & 1u)) >> 16;
    return (ushort_t)r;
}
__device__ inline void stage16(const ushort_t* g, ushort_t* s) {
    __builtin_amdgcn_global_load_lds((const __attribute__((address_space(1))) void*)g,
                                     (__attribute__((address_space(3))) void*)s, 16, 0, 0);
}
// swizzle position function: folds row bits 3-4 so stride-8 lane groups (HW b128
// conflict granularity; inferred R5/R6 counter A/B) never exceed 2-way.
__device__ inline int swz(int r) { return (r & 7) ^ ((r >> 3) & 3); }
// stage one 128x64 bf16 tile; LDS slot e (row e>>3, pos e&7) holds global chunk (e&7)^swz(row)
__device__ inline void stage_tile(const ushort_t* G, int ld, int k0, ushort_t* S, int tid) {
#pragma unroll
    for (int t = 0; t < 4; ++t) {
        int e = tid + t * 256;
        int row = e >> 3;
        int sw = ((e & 7) ^ swz(row)) * 8;
        stage16(G + (long long)row * ld + k0 + sw, &S[e * 8]);
    }
}
__device__ inline bf16x8 ldfrag(const ushort_t* S, int r, int c) {
    return *(const bf16x8*)&S[r * BK + ((c ^ swz(r)) * 8)];
}
// XCD-aware tile decode for 128^2 kernels (B-resident mapping; good when B is small
// relative to A re-reads, e.g. k_gemm_nt).
__device__ inline void tile_decode(int& m0, int& n0) {
    const int nx = gridDim.x;
    int lin = blockIdx.y * nx + blockIdx.x;
    if ((nx & 7) == 0) {
        int q = nx >> 3;
        int k = lin & 7, s = lin >> 3;
        n0 = (k * q + s % q) * BN;
        m0 = (s / q) * BM;
    } else {
        m0 = blockIdx.y * BM;
        n0 = blockIdx.x * BN;
    }
}

// ==================== 256-wide pipelined GEMM cores ====================
// Counted-vmcnt schedule (loads never drained to 0 in steady state); K-tile (64)
// split into two contiguous 16KB-region K-halves (global_load_lds linear dest);
// 2-bit XOR swizzle keeps ds_read_b128 at <=2-way bank aliasing (free, m136).
// R3: merged 4-phase -> 2-phase per K-tile: 16-MFMA clusters per barrier-pair
// (halves barrier count; barrier skew amortized over 2x matrix work).

#define SBAR() __builtin_amdgcn_sched_barrier(0)
#define BARRIER() do { SBAR(); __builtin_amdgcn_s_barrier(); SBAR(); } while (0)
#define WAITV(N) asm volatile("s_waitcnt vmcnt(" #N ")" ::: "memory")

__device__ inline int sw2(int r) { return ((r) & 3) ^ ((r >> 3) & 3); }

// stage K-half h (cols 32h..32h+31) of a 256-row tile (2 loads/thread).
// slot s=(r*4+q) -> LDS half region Sbuf + h*8192; slot holds chunk 4h + (q^sw2(r)).
__device__ inline void stage_half(const ushort_t* G, int ldg, int kElem,
                                  ushort_t* Sbuf, int h, int tid) {
#pragma unroll
    for (int i2 = 0; i2 < 2; ++i2) {
        int s = tid + i2 * 512;
        int r = s >> 2, q = s & 3;
        int c = 4 * h + (q ^ sw2(r));
        stage16(G + (long long)r * ldg + kElem + c * 8, Sbuf + h * 8192 + s * 8);
    }
}
// stage K-half h of a 128-row tile (1 load/thread); half region stride 4096 ushorts.
__device__ inline void stage_halfA(const ushort_t* G, int ldg,
                                   ushort_t* Sbuf, int h, int tid) {
    int r = tid >> 2, q = tid & 3;
    int c = 4 * h + (q ^ sw2(r));
    stage16(G + (long long)r * ldg + c * 8, Sbuf + h * 4096 + tid * 8);
}
// read the 8-bf16 fragment (row r, K-chunk c in 0..7); hs = ushorts per half region
__device__ inline bf16x8 ldfrag2(const ushort_t* Sbuf, int r, int c, int hs) {
    int h = c >> 2;
    int lp = (c ^ sw2(r)) & 3;
    return *(const bf16x8*)&Sbuf[h * hs + r * 32 + lp * 8];
}

// ---- 256x256 core (8 waves of 128x64), 2 phases per K-tile ------------------
template <int KS0>   // 0 (K-half 0) or 2 (K-half 1)
__device__ __forceinline__ void phase_load2(const ushort_t* cA, const ushort_t* cB,
                                            int wr, int wc, int l32, int hl,
                                            bf16x8 af_[4][2], bf16x8 bf_[2][2]) {
#pragma unroll
    for (int k2 = 0; k2 < 2; ++k2) {
        int c = (KS0 + k2) * 2 + hl;
#pragma unroll
        for (int m2 = 0; m2 < 4; ++m2)
            af_[m2][k2] = ldfrag2(cA, wr * 128 + m2 * 32 + l32, c, 8192);
#pragma unroll
        for (int n2 = 0; n2 < 2; ++n2)
            bf_[n2][k2] = ldfrag2(cB, wc * 64 + n2 * 32 + l32, c, 8192);
    }
}
__device__ __forceinline__ void phase_mfma2(bf16x8 af_[4][2], bf16x8 bf_[2][2],
                                            f32x16 (&acc)[4][2]) {
#pragma unroll
    for (int k2 = 0; k2 < 2; ++k2)
#pragma unroll
        for (int m2 = 0; m2 < 4; ++m2)
#pragma unroll
            for (int n2 = 0; n2 < 2; ++n2)
                acc[m2][n2] = __builtin_amdgcn_mfma_f32_32x32x16_bf16(
                    af_[m2][k2], bf_[n2][k2], acc[m2][n2], 0, 0, 0);
}

// requires K % 64 == 0 and K >= 128
// vmcnt proof (per-thread, in-order retirement): issue cadence is 4 loads/phase
// (A-half 2 + B-half 2). At any phase's WAITV(8), the 8 newest outstanding are
// exactly {prev phase's 4, this phase's 4}; everything older — in particular the
// K-half consumed by the NEXT phase — is forced complete. Tail phases tighten
// 8 -> 4 -> 0 as prefetch stops.
__device__ __forceinline__ void gemm256_core(const ushort_t* __restrict__ Ag, int lda,
                                             const ushort_t* __restrict__ Bg, int ldb,
                                             int K, ushort_t* smem, int tid,
                                             int wr, int wc, int l32, int hl,
                                             f32x16 (&acc)[4][2]) {
    ushort_t* A0s = smem;
    ushort_t* A1s = smem + 16384;
    ushort_t* B0s = smem + 32768;
    ushort_t* B1s = smem + 49152;
    const int NT = K >> 6;

    // prologue: A0(0),B0(0) h0+h1, A1(1),B1(1) h0; wait for tile-0 h0.
    stage_half(Ag, lda, 0, A0s, 0, tid);
    stage_half(Bg, ldb, 0, B0s, 0, tid);
    stage_half(Ag, lda, 0, A0s, 1, tid);
    stage_half(Bg, ldb, 0, B0s, 1, tid);
    stage_half(Ag, lda, 64, A1s, 0, tid);
    stage_half(Bg, ldb, 64, B1s, 0, tid);
    WAITV(8);
    BARRIER();

    for (int kt = 0; kt < NT; ++kt) {
        ushort_t* cA = (kt & 1) ? A1s : A0s;
        ushort_t* cB = (kt & 1) ? B1s : B0s;
        ushort_t* nA = (kt & 1) ? A0s : A1s;
        ushort_t* nB = (kt & 1) ? B0s : B1s;
        const bool h1 = (kt + 1 < NT), h2 = (kt + 2 < NT);
        const int kE1 = (kt + 1) << 6, kE2 = (kt + 2) << 6;
        bf16x8 af_[4][2], bf_[2][2];
        // ---- Phase A: consume K-half 0 of tile kt; prefetch h1 of tile kt+1.
        if (h1) {
            stage_half(Ag, lda, kE1, nA, 1, tid);
            stage_half(Bg, ldb, kE1, nB, 1, tid);
        }
        phase_load2<0>(cA, cB, wr, wc, l32, hl, af_, bf_);
        BARRIER();
        __builtin_amdgcn_s_setprio(1);
        phase_mfma2(af_, bf_, acc);
        __builtin_amdgcn_s_setprio(0);
        if (h1) { WAITV(8); } else { WAITV(0); }   // forces h1(kt) landed
        BARRIER();
        // ---- Phase B: consume K-half 1 of tile kt; prefetch h0 of tile kt+2
        // (into the buffer whose reads completed in Phase A — no WAR hazard).
        if (h2) {
            stage_half(Ag, lda, kE2, cA, 0, tid);
            stage_half(Bg, ldb, kE2, cB, 0, tid);
        }
        phase_load2<2>(cA, cB, wr, wc, l32, hl, af_, bf_);
        BARRIER();
        __builtin_amdgcn_s_setprio(1);
        phase_mfma2(af_, bf_, acc);
        __builtin_amdgcn_s_setprio(0);
        if (h2) { WAITV(8); } else if (h1) { WAITV(4); } else { WAITV(0); }  // forces h0(kt+1)
        BARRIER();
    }
}

// ---- 256^2 fused gate_up GEMM + in-register SiLU (weights row-PERMUTED:
// permuted row 64q+s = gate row 32q+s (s<32) else up row 32q+s-32, so
// acc[mi][0]=gate, acc[mi][1]=up for the SAME h column). grid (32,32), 512 thr.
__global__ __launch_bounds__(512, 2)
void k_gemm256_silu(const ushort_t* __restrict__ A, const ushort_t* __restrict__ Bp,
                    ushort_t* __restrict__ H) {
    extern __shared__ __attribute__((aligned(16))) ushort_t smem2[];
    const int tid = threadIdx.x;
    const int lane = tid & 63, l32 = lane & 31, hl = lane >> 5;
    const int wv = tid >> 6, wr = wv >> 2, wc = wv & 3;
    // XCD-aware 256-tile decode: XCD k owns 4 n-tiles, sweeps m (nwg=1024, %8==0)
    int lin = blockIdx.y * 32 + blockIdx.x;
    int k8 = lin & 7, s = lin >> 3;
    int n0 = (k8 * 4 + (s & 3)) * 256;
    int m0 = (s >> 2) * 256;
    const ushort_t* Ag = A + (long long)m0 * 1024;
    const ushort_t* Bg = Bp + (long long)n0 * 1024;
    f32x16 acc[4][2];
#pragma unroll
    for (int i = 0; i < 4; ++i) { acc[i][0] = (f32x16)(0.f); acc[i][1] = (f32x16)(0.f); }
    gemm256_core(Ag, 1024, Bg, 1024, 1024, smem2, tid, wr, wc, l32, hl, acc);
    const int hc = (n0 >> 1) + wc * 32 + l32;
#pragma unroll
    for (int mi = 0; mi < 4; ++mi)
#pragma unroll
        for (int reg = 0; reg < 16; ++reg) {
            int row = m0 + wr * 128 + mi * 32 + (reg & 3) + 8 * (reg >> 2) + 4 * hl;
            float g = acc[mi][0][reg], u = acc[mi][1][reg];
            float sg = g / (1.f + __expf(-g));
            H[(long long)row * 4096 + hc] = f2b(sg * u);
        }
}

// ---- 256^2 triangular P GEMM: one block per (b,i,j) pair (exactly one 256^2
// tile). Bijective XCD remap: XCD x gets 30 consecutive pairIdx -> same-i runs
// share an XCD's L2 (h_i stays hot).
__global__ __launch_bounds__(512, 2)
void k_gemm256_tri(const ushort_t* __restrict__ Hh, ushort_t* __restrict__ P) {
    extern __shared__ __attribute__((aligned(16))) ushort_t smem2[];
    const int tid = threadIdx.x;
    const int lane = tid & 63, l32 = lane & 31, hl = lane >> 5;
    const int wv = tid >> 6, wr = wv >> 2, wc = wv & 3;
    int pairIdx = (blockIdx.x & 7) * 30 + (blockIdx.x >> 3);   // 240 = 8*30
    const int bb = pairIdx / 120;
    int p = pairIdx % 120;
    int i = 1, rem = p;
    while (rem >= i) { rem -= i; ++i; }
    const int j = rem;
    const ushort_t* Ag = Hh + (long long)bb * 4096 * 4096 + (long long)(i * 256) * 4096;
    const ushort_t* Bg = Hh + (long long)bb * 4096 * 4096 + (long long)(j * 256) * 4096;
    f32x16 acc[4][2];
#pragma unroll
    for (int a = 0; a < 4; ++a) { acc[a][0] = (f32x16)(0.f); acc[a][1] = (f32x16)(0.f); }
    gemm256_core(Ag, 4096, Bg, 4096, 4096, smem2, tid, wr, wc, l32, hl, acc);
    ushort_t* Pp = P + (long long)bb * 4096 * 4096;
#pragma unroll
    for (int mi = 0; mi < 4; ++mi)
#pragma unroll
        for (int nj = 0; nj < 2; ++nj) {
            int col = j * 256 + wc * 64 + nj * 32 + l32;
#pragma unroll
            for (int reg = 0; reg < 16; ++reg) {
                int row = i * 256 + wr * 128 + mi * 32 + (reg & 3) + 8 * (reg >> 2) + 4 * hl;
                Pp[(long long)row * 4096 + col] = f2b(acc[mi][nj][reg]);
            }
        }
}

// ==================== fused output GEMM, pipelined 128x256 ====================
// out[b,ii] = [h_ii | P_ii,0:ii*C] @ [wdown | tpT]^T, K = 4096 + ii*256.
// 256 blocks (512 thr, 8 waves of 64x64, 96 KiB LDS -> 1 block/CU, all resident).
// A-resident XCD decode: XCD x owns z in {4x..4x+3} x all 8 (m,n)-tiles.
__device__ __forceinline__ void oload_ks(const ushort_t* cA, const ushort_t* cB,
                                         int ks0, int wr, int wc, int l32, int hl,
                                         bf16x8 af_[2][2], bf16x8 bf_[2][2]) {
#pragma unroll
    for (int k2 = 0; k2 < 2; ++k2) {
        int c = (ks0 + k2) * 2 + hl;
#pragma unroll
        for (int m2 = 0; m2 < 2; ++m2)
            af_[m2][k2] = ldfrag2(cA, wr * 64 + m2 * 32 + l32, c, 4096);
#pragma unroll
        for (int n2 = 0; n2 < 2; ++n2)
            bf_[n2][k2] = ldfrag2(cB, wc * 64 + n2 * 32 + l32, c, 8192);
    }
}
__device__ __forceinline__ void omfma(bf16x8 af_[2][2], bf16x8 bf_[2][2],
                                      f32x16 (&acc)[2][2]) {
#pragma unroll
    for (int k2 = 0; k2 < 2; ++k2)
#pragma unroll
        for (int m2 = 0; m2 < 2; ++m2)
#pragma unroll
            for (int n2 = 0; n2 < 2; ++n2)
                acc[m2][n2] = __builtin_amdgcn_mfma_f32_32x32x16_bf16(
                    af_[m2][k2], bf_[n2][k2], acc[m2][n2], 0, 0, 0);
}

__global__ __launch_bounds__(512, 2)
void k_gemm256_out(const ushort_t* __restrict__ h, const ushort_t* __restrict__ wdown,
                   const ushort_t* __restrict__ P, const ushort_t* __restrict__ tpT,
                   float* __restrict__ out) {
    constexpr int T = 4096, D = 1024, F = 4096, C = 256, K1 = 4096;
    extern __shared__ __attribute__((aligned(16))) ushort_t smem2[];
    const int tid = threadIdx.x;
    const int lane = tid & 63, l32 = lane & 31, hl = lane >> 5;
    const int wv = tid >> 6, wr = wv >> 2, wc = wv & 3;   // wr 0..1, wc 0..3

    // A-resident XCD decode: physical bx -> XCD = bx&7 owns logical 32-chunk.
    const int bx = blockIdx.x;
    const int logical = (bx & 7) * 32 + (bx >> 3);        // 256 blocks
    const int z = logical >> 3, t = logical & 7;          // z 0..31
    const int bb = z >> 4, ii = z & 15;
    const int m0 = (t >> 2) * 128, n0 = (t & 3) * 256;
    const int K = K1 + ii * C;

    const ushort_t* hA = h + (long long)bb * T * F + (long long)(ii * C + m0) * F;
    const ushort_t* pA = P + (long long)bb * T * T + (long long)(ii * C + m0) * T;
    const ushort_t* wB = wdown + (long long)n0 * F;
    const ushort_t* tB = tpT + (long long)bb * D * T + (long long)n0 * T;

    ushort_t* A0s = smem2;              // 8192 ushorts each (16 KB)
    ushort_t* A1s = smem2 + 8192;
    ushort_t* B0s = smem2 + 16384;      // 16384 ushorts each (32 KB)
    ushort_t* B1s = smem2 + 32768;

    f32x16 acc[2][2];
#pragma unroll
    for (int a = 0; a < 2; ++a)
#pragma unroll
        for (int c = 0; c < 2; ++c) acc[a][c] = (f32x16)(0.f);

    auto srcA = [&](int kE) { return kE < K1 ? hA + kE : pA + (kE - K1); };
    auto srcB = [&](int kE) { return kE < K1 ? wB + kE : tB + (kE - K1); };

    const int NT = K >> 6;   // >= 64

    // prologue: A(0)h0,B(0)h0,A(0)h1,B(0)h1,A(1)h0,B(1)h0  (9 loads)
    stage_halfA(srcA(0), F, A0s, 0, tid);
    stage_half (srcB(0), F, 0, B0s, 0, tid);
    stage_halfA(srcA(0), F, A0s, 1, tid);
    stage_half (srcB(0), F, 0, B0s, 1, tid);
    stage_halfA(srcA(64), F, A1s, 0, tid);
    stage_half (srcB(64), F, 0, B1s, 0, tid);
    WAITV(6);
    BARRIER();

    for (int kt = 0; kt < NT; ++kt) {
        ushort_t* cA = (kt & 1) ? A1s : A0s;
        ushort_t* cB = (kt & 1) ? B1s : B0s;
        ushort_t* nA = (kt & 1) ? A0s : A1s;
        ushort_t* nB = (kt & 1) ? B0s : B1s;
        const bool h1 = (kt + 1 < NT), h2 = (kt + 2 < NT);
        const int kE1 = (kt + 1) << 6, kE2 = (kt + 2) << 6;
        bf16x8 af_[2][2], bf_[2][2];
        // ---- PH1: issue A(kt+1)h1 + B(kt+1)h1; compute ks 0-1; wait A/B(kt)h1
        if (h1) {
            stage_halfA(srcA(kE1), F, nA, 1, tid);
            stage_half (srcB(kE1), F, 0, nB, 1, tid);
        }
        oload_ks(cA, cB, 0, wr, wc, l32, hl, af_, bf_);
        BARRIER();
        __builtin_amdgcn_s_setprio(1);
        omfma(af_, bf_, acc);
        __builtin_amdgcn_s_setprio(0);
        if (h1) { WAITV(6); } else { WAITV(0); }
        BARRIER();
        // ---- PH2: issue A(kt+2)h0 + B(kt+2)h0; compute ks 2-3; wait A/B(kt+1)h0
        if (h2) {
            stage_halfA(srcA(kE2), F, cA, 0, tid);
            stage_half (srcB(kE2), F, 0, cB, 0, tid);
        }
        oload_ks(cA, cB, 2, wr, wc, l32, hl, af_, bf_);
        BARRIER();
        __builtin_amdgcn_s_setprio(1);
        omfma(af_, bf_, acc);
        __builtin_amdgcn_s_setprio(0);
        if (h2) { WAITV(6); } else { if (h1) { WAITV(3); } else { WAITV(0); } }
        BARRIER();
    }

    float* Op = out + (long long)bb * T * D + (long long)(ii * C) * D;
#pragma unroll
    for (int mi = 0; mi < 2; ++mi)
#pragma unroll
        for (int nj = 0; nj < 2; ++nj) {
            int col = n0 + wc * 64 + nj * 32 + l32;
#pragma unroll
            for (int reg = 0; reg < 16; ++reg) {
                int row = m0 + wr * 64 + mi * 32 + (reg & 3) + 8 * (reg >> 2) + 4 * hl;
                Op[(long long)row * D + col] = acc[mi][nj][reg];
            }
        }
}

// ---------- fused prep: fp32->bf16 converts (x|wgu|proj|wdown) + causal conv ----------
// permW: write wgu in the gate/up-interleaved row order for k_gemm256_silu.
__global__ void k_prep(const float* __restrict__ x, const float* __restrict__ wgu,
                       const float* __restrict__ proj, const float* __restrict__ wdown,
                       const float* __restrict__ tt, const float* __restrict__ cw,
                       const float* __restrict__ cb,
                       ushort_t* __restrict__ xb, ushort_t* __restrict__ gb,
                       ushort_t* __restrict__ pb, ushort_t* __restrict__ wb,
                       ushort_t* __restrict__ tb, int permW) {
    constexpr int T = 4096, D = 1024;
    int blk = blockIdx.x;
    if (blk < 21504) {
        // converts, float4-wide: x 2097152 | wgu 2097152 | proj 262144 | wdown 1048576 units
        int i = blk * 256 + threadIdx.x;
        const float* src; ushort_t* dst; int off; int dstoff;
        if (i < 2097152)      { src = x;     dst = xb; off = i; dstoff = off; }
        else if (i < 4194304) {
            src = wgu; dst = gb; off = i - 2097152;
            if (permW) {
                int r = off >> 8, cu = off & 255;
                int pr = (r < 4096) ? (((r >> 5) << 6) + (r & 31))
                                    : ((((r - 4096) >> 5) << 6) + 32 + ((r - 4096) & 31));
                dstoff = (pr << 8) + cu;
            } else dstoff = off;
        }
        else if (i < 4456448) { src = proj;  dst = pb; off = i - 4194304; dstoff = off; }
        else                  { src = wdown; dst = wb; off = i - 4456448; dstoff = off; }
        float4 v = ((const float4*)src)[off];
        ushort4 o; o.x = f2b(v.x); o.y = f2b(v.y); o.z = f2b(v.z); o.w = f2b(v.w);
        ((ushort4*)dst)[dstoff] = o;
    } else {
        // causal depthwise conv (K=5)
        int idx = (blk - 21504) * 256 + threadIdx.x;
        int d = idx % D;
        int t = (idx / D) % T;
        int b = idx / (D * T);
        float acc = cb[d];
#pragma unroll
        for (int k = 0; k < 5; ++k) {
            int ts = t - 4 + k;
            if (ts >= 0) acc += tt[(long long)b * T * D + (long long)ts * D + d] * cw[d * 5 + k];
        }
        tb[idx] = f2b(acc);
    }
}

// ---------- batched bf16 NT GEMM (bf16 out): C[m,n] = scale * sum_k A[m,k]*B[n,k] ----------
__global__ __launch_bounds__(256, 4)
void k_gemm_nt(const ushort_t* __restrict__ A, const ushort_t* __restrict__ B,
               ushort_t* __restrict__ C, int K, int lda, int ldb, int ldc,
               long long sAb, long long sBb, long long sCb, float scale) {
    __shared__ __attribute__((aligned(16))) ushort_t sA[BM * BK];
    __shared__ __attribute__((aligned(16))) ushort_t sB[BN * BK];

    int m0, n0;
    tile_decode(m0, n0);
    const int bb = blockIdx.z;
    const ushort_t* Ab = A + bb * sAb + (long long)m0 * lda;
    const ushort_t* Bb = B + bb * sBb + (long long)n0 * ldb;

    const int tid = threadIdx.x;
    const int lane = tid & 63, l32 = lane & 31, half = lane >> 5;
    const int wave = tid >> 6;
    const int wm = (wave >> 1) * 64, wn = (wave & 1) * 64;

    f32x16 acc[2][2];
#pragma unroll
    for (int i = 0; i < 2; ++i)
#pragma unroll
        for (int j = 0; j < 2; ++j) acc[i][j] = (f32x16)(0.f);

    for (int k0 = 0; k0 < K; k0 += BK) {
        __syncthreads();
        stage_tile(Ab, lda, k0, sA, tid);
        stage_tile(Bb, ldb, k0, sB, tid);
        __syncthreads();
#pragma unroll
        for (int ks = 0; ks < 4; ++ks) {
            bf16x8 af[2], bfr[2];
#pragma unroll
            for (int mi = 0; mi < 2; ++mi)
                af[mi] = ldfrag(sA, wm + mi * 32 + l32, ks * 2 + half);
#pragma unroll
            for (int nj = 0; nj < 2; ++nj)
                bfr[nj] = ldfrag(sB, wn + nj * 32 + l32, ks * 2 + half);
#pragma unroll
            for (int mi = 0; mi < 2; ++mi)
#pragma unroll
                for (int nj = 0; nj < 2; ++nj)
                    acc[mi][nj] = __builtin_amdgcn_mfma_f32_32x32x16_bf16(af[mi], bfr[nj], acc[mi][nj], 0, 0, 0);
        }
    }

    ushort_t* Cp = C + bb * sCb;
#pragma unroll
    for (int mi = 0; mi < 2; ++mi)
#pragma unroll
        for (int nj = 0; nj < 2; ++nj) {
            int col = n0 + wn + nj * 32 + l32;
#pragma unroll
            for (int reg = 0; reg < 16; ++reg) {
                int row = m0 + wm + mi * 32 + (reg & 3) + 8 * (reg >> 2) + 4 * half;
                Cp[(long long)row * ldc + col] = f2b(acc[mi][nj][reg] * scale);
            }
        }
}

// ---------- fallback fused gate_up GEMM + SiLU (unpermuted weights) ----------
__global__ __launch_bounds__(256)
void k_gemm_silu(const ushort_t* __restrict__ A, const ushort_t* __restrict__ Bg,
                 const ushort_t* __restrict__ Bu, ushort_t* __restrict__ H,
                 int K, int lda, int ldb, int ldh) {
    __shared__ __attribute__((aligned(16))) ushort_t sA[BM * BK];
    __shared__ __attribute__((aligned(16))) ushort_t sBg[BN * BK];
    __shared__ __attribute__((aligned(16))) ushort_t sBu[BN * BK];

    int m0, n0;
    tile_decode(m0, n0);
    const ushort_t* Ab = A + (long long)m0 * lda;
    const ushort_t* Bgb = Bg + (long long)n0 * ldb;
    const ushort_t* Bub = Bu + (long long)n0 * ldb;

    const int tid = threadIdx.x;
    const int lane = tid & 63, l32 = lane & 31, half = lane >> 5;
    const int wave = tid >> 6;
    const int wm = (wave >> 1) * 64, wn = (wave & 1) * 64;

    f32x16 ag[2][2], au[2][2];
#pragma unroll
    for (int i = 0; i < 2; ++i)
#pragma unroll
        for (int j = 0; j < 2; ++j) { ag[i][j] = (f32x16)(0.f); au[i][j] = (f32x16)(0.f); }

    for (int k0 = 0; k0 < K; k0 += BK) {
        __syncthreads();
        stage_tile(Ab, lda, k0, sA, tid);
        stage_tile(Bgb, ldb, k0, sBg, tid);
        stage_tile(Bub, ldb, k0, sBu, tid);
        __syncthreads();
#pragma unroll
        for (int ks = 0; ks < 4; ++ks) {
            bf16x8 af[2], bg[2], bu[2];
#pragma unroll
            for (int mi = 0; mi < 2; ++mi)
                af[mi] = ldfrag(sA, wm + mi * 32 + l32, ks * 2 + half);
#pragma unroll
            for (int nj = 0; nj < 2; ++nj) {
                bg[nj] = ldfrag(sBg, wn + nj * 32 + l32, ks * 2 + half);
                bu[nj] = ldfrag(sBu, wn + nj * 32 + l32, ks * 2 + half);
            }
#pragma unroll
            for (int mi = 0; mi < 2; ++mi)
#pragma unroll
                for (int nj = 0; nj < 2; ++nj) {
                    ag[mi][nj] = __builtin_amdgcn_mfma_f32_32x32x16_bf16(af[mi], bg[nj], ag[mi][nj], 0, 0, 0);
                    au[mi][nj] = __builtin_amdgcn_mfma_f32_32x32x16_bf16(af[mi], bu[nj], au[mi][nj], 0, 0, 0);
                }
        }
    }

#pragma unroll
    for (int mi = 0; mi < 2; ++mi)
#pragma unroll
        for (int nj = 0; nj < 2; ++nj) {
            int col = n0 + wn + nj * 32 + l32;
#pragma unroll
            for (int reg = 0; reg < 16; ++reg) {
                int row = m0 + wm + mi * 32 + (reg & 3) + 8 * (reg >> 2) + 4 * half;
                float g = ag[mi][nj][reg], u = au[mi][nj][reg];
                float s = g / (1.f + __expf(-g));
                H[(long long)row * ldh + col] = f2b(s * u);
            }
        }
}

// ---------- fallback triangular P GEMM (128^2 tiles) ----------
__global__ __launch_bounds__(256, 4)
void k_gemm_tri(const ushort_t* __restrict__ H, ushort_t* __restrict__ P,
                int K, int ldh, int ldp, long long sHb, long long sPb) {
    __shared__ __attribute__((aligned(16))) ushort_t sA[BM * BK];
    __shared__ __attribute__((aligned(16))) ushort_t sB[BN * BK];

    const int lin = blockIdx.x;
    const int g = lin >> 5, w = lin & 31;
    const int xk = w & 7, t = w >> 3;
    int pairIdx = g * 8 + xk;            // 0..239
    const int bb = pairIdx / 120;
    int p = pairIdx % 120;
    int i = 1, rem = p;
    while (rem >= i) { rem -= i; ++i; }
    const int j = rem;
    const int m0 = (t >> 1) * BM, n0 = (t & 1) * BN;

    const ushort_t* Ab = H + bb * sHb + (long long)(i * 256 + m0) * ldh;
    const ushort_t* Bb = H + bb * sHb + (long long)(j * 256 + n0) * ldh;

    const int tid = threadIdx.x;
    const int lane = tid & 63, l32 = lane & 31, half = lane >> 5;
    const int wave = tid >> 6;
    const int wm = (wave >> 1) * 64, wn = (wave & 1) * 64;

    f32x16 acc[2][2];
#pragma unroll
    for (int a = 0; a < 2; ++a)
#pragma unroll
        for (int c = 0; c < 2; ++c) acc[a][c] = (f32x16)(0.f);

    for (int k0 = 0; k0 < K; k0 += BK) {
        __syncthreads();
        stage_tile(Ab, ldh, k0, sA, tid);
        stage_tile(Bb, ldh, k0, sB, tid);
        __syncthreads();
#pragma unroll
        for (int ks = 0; ks < 4; ++ks) {
            bf16x8 af[2], bfr[2];
#pragma unroll
            for (int mi = 0; mi < 2; ++mi)
                af[mi] = ldfrag(sA, wm + mi * 32 + l32, ks * 2 + half);
#pragma unroll
            for (int nj = 0; nj < 2; ++nj)
                bfr[nj] = ldfrag(sB, wn + nj * 32 + l32, ks * 2 + half);
#pragma unroll
            for (int mi = 0; mi < 2; ++mi)
#pragma unroll
                for (int nj = 0; nj < 2; ++nj)
                    acc[mi][nj] = __builtin_amdgcn_mfma_f32_32x32x16_bf16(af[mi], bfr[nj], acc[mi][nj], 0, 0, 0);
        }
    }

    ushort_t* Pp = P + bb * sPb;
#pragma unroll
    for (int mi = 0; mi < 2; ++mi)
#pragma unroll
        for (int nj = 0; nj < 2; ++nj) {
            int col = j * 256 + n0 + wn + nj * 32 + l32;
#pragma unroll
            for (int reg = 0; reg < 16; ++reg) {
                int row = i * 256 + m0 + wm + mi * 32 + (reg & 3) + 8 * (reg >> 2) + 4 * half;
                Pp[(long long)row * ldp + col] = f2b(acc[mi][nj][reg]);
            }
        }
}

// ---------- fallback fused output GEMM (128^2) ----------
__global__ __launch_bounds__(256, 4)
void k_gemm_out(const ushort_t* __restrict__ h, const ushort_t* __restrict__ wdown,
                const ushort_t* __restrict__ P, const ushort_t* __restrict__ tpT,
                float* __restrict__ out) {
    constexpr int T = 4096, D = 1024, F = 4096, C = 256, K1 = 4096;
    __shared__ __attribute__((aligned(16))) ushort_t sA[BM * BK];
    __shared__ __attribute__((aligned(16))) ushort_t sB[BN * BK];

    const int z = blockIdx.z, bb = z >> 4, ii = z & 15;
    const int K2 = ii * C;
    int m0, n0;
    tile_decode(m0, n0);

    const ushort_t* A1 = h + (long long)bb * T * F + (long long)(ii * C + m0) * F;
    const ushort_t* B1 = wdown + (long long)n0 * F;
    const ushort_t* A2 = P + (long long)bb * T * T + (long long)(ii * C + m0) * T;
    const ushort_t* B2 = tpT + (long long)bb * D * T + (long long)n0 * T;

    const int tid = threadIdx.x;
    const int lane = tid & 63, l32 = lane & 31, half = lane >> 5;
    const int wave = tid >> 6;
    const int wm = (wave >> 1) * 64, wn = (wave & 1) * 64;

    f32x16 acc[2][2];
#pragma unroll
    for (int i = 0; i < 2; ++i)
#pragma unroll
        for (int j = 0; j < 2; ++j) acc[i][j] = (f32x16)(0.f);

    const int K = K1 + K2;
    for (int k0 = 0; k0 < K; k0 += BK) {
        const ushort_t* As = (k0 < K1) ? A1 + k0 : A2 + (k0 - K1);
        const ushort_t* Bs = (k0 < K1) ? B1 + k0 : B2 + (k0 - K1);
        __syncthreads();
        stage_tile(As, 4096, 0, sA, tid);
        stage_tile(Bs, 4096, 0, sB, tid);
        __syncthreads();
#pragma unroll
        for (int ks = 0; ks < 4; ++ks) {
            bf16x8 af[2], bfr[2];
#pragma unroll
            for (int mi = 0; mi < 2; ++mi)
                af[mi] = ldfrag(sA, wm + mi * 32 + l32, ks * 2 + half);
#pragma unroll
            for (int nj = 0; nj < 2; ++nj)
                bfr[nj] = ldfrag(sB, wn + nj * 32 + l32, ks * 2 + half);
#pragma unroll
            for (int mi = 0; mi < 2; ++mi)
#pragma unroll
                for (int nj = 0; nj < 2; ++nj)
                    acc[mi][nj] = __builtin_amdgcn_mfma_f32_32x32x16_bf16(af[mi], bfr[nj], acc[mi][nj], 0, 0, 0);
        }
    }

    float* Op = out + (long long)bb * T * D + (long long)ii * C * D;
#pragma unroll
    for (int mi = 0; mi < 2; ++mi)
#pragma unroll
        for (int nj = 0; nj < 2; ++nj) {
            int col = n0 + wn + nj * 32 + l32;
#pragma unroll
            for (int reg = 0; reg < 16; ++reg) {
                int row = m0 + wm + mi * 32 + (reg & 3) + 8 * (reg >> 2) + 4 * half;
                Op[(long long)row * D + col] = acc[mi][nj][reg];
            }
        }
}

// ---------- launch ----------
static int g_big = -1;

extern "C" void kernel_launch(void* const* d_in, const int* in_sizes, int n_in,
                              void* d_out, int out_size, void* d_ws, size_t ws_size,
                              hipStream_t stream) {
    const float* x         = (const float*)d_in[0];
    const float* ttt_tgt   = (const float*)d_in[1];
    const float* w_gate_up = (const float*)d_in[2];
    const float* w_down    = (const float*)d_in[3];
    const float* ttt_proj  = (const float*)d_in[4];
    const float* conv_w    = (const float*)d_in[5];
    const float* conv_b    = (const float*)d_in[6];
    float* out = (float*)d_out;
    (void)in_sizes; (void)n_in; (void)out_size; (void)ws_size;

    constexpr int Bb = 2, T = 4096, D = 1024, F = 4096, C = 256;
    constexpr float LR = 0.01f;

    // one-time: opt in to big dynamic LDS for the pipelined kernels; if the
    // runtime refuses, fall back to the 128^2 path (status-quo performance).
    if (g_big < 0) {
        hipError_t e1 = hipFuncSetAttribute((const void*)k_gemm256_silu,
                                            hipFuncAttributeMaxDynamicSharedMemorySize, 131072);
        hipError_t e2 = hipFuncSetAttribute((const void*)k_gemm256_tri,
                                            hipFuncAttributeMaxDynamicSharedMemorySize, 131072);
        hipError_t e3 = hipFuncSetAttribute((const void*)k_gemm256_out,
                                            hipFuncAttributeMaxDynamicSharedMemorySize, 98304);
        g_big = (e1 == hipSuccess && e2 == hipSuccess && e3 == hipSuccess) ? 1 : 0;
    }

    // workspace (154 MB):
    //   [0,64M): x_bf(16M) | wgu_bf(16M) | t_bf(16M) | scratch  -> later aliased by P (B,T,T) bf16
    //   [64M..): proj_bf 2M | wdown_bf 8M | tpT 16M | h 64M
    char* ws = (char*)d_ws;
    ushort_t* x_bf     = (ushort_t*)(ws);
    ushort_t* wgu_bf   = (ushort_t*)(ws + 16777216LL);
    ushort_t* t_bf     = (ushort_t*)(ws + 2 * 16777216LL);
    ushort_t* P        = (ushort_t*)(ws);
    ushort_t* proj_bf  = (ushort_t*)(ws + 67108864LL);
    ushort_t* wdown_bf = (ushort_t*)(ws + 67108864LL + 2097152LL);
    ushort_t* tpT      = (ushort_t*)(ws + 67108864LL + 2097152LL + 8388608LL);
    ushort_t* h        = (ushort_t*)(ws + 67108864LL + 2097152LL + 8388608LL + 16777216LL);

    // 1) fused prep: converts (+ optional gate/up row interleave) + causal conv
    k_prep<<<21504 + 32768, 256, 0, stream>>>(x, w_gate_up, ttt_proj, w_down,
                                              ttt_tgt, conv_w, conv_b,
                                              x_bf, wgu_bf, proj_bf, wdown_bf, t_bf, g_big);

    // 2) tpT[b] = LR * (proj @ t[b]^T) : M=D, N=T, K=D -> bf16 (B,D,T)
    k_gemm_nt<<<dim3(T / BN, D / BM, Bb), 256, 0, stream>>>(
        proj_bf, t_bf, tpT, D, D, D, T,
        0, (long long)T * D, (long long)D * T, LR);

    // 3) h = silu(x@Wg^T)*(x@Wu^T) : M=B*T=8192, N(permuted)=8192, K=1024
    if (g_big) {
        k_gemm256_silu<<<dim3(32, 32, 1), 512, 131072, stream>>>(x_bf, wgu_bf, h);
    } else {
        k_gemm_silu<<<dim3(F / BN, (Bb * T) / BM, 1), 256, 0, stream>>>(
            x_bf, wgu_bf, wgu_bf + (long long)F * D, h, D, D, D, F);
    }

    // 4) P lower chunk-blocks: P[b, i*C.., j*C..] = h_i h_j^T, j<i
    if (g_big) {
        k_gemm256_tri<<<dim3(240, 1, 1), 512, 131072, stream>>>(h, P);
    } else {
        k_gemm_tri<<<dim3(960, 1, 1), 256, 0, stream>>>(
            h, P, F, F, T, (long long)T * F, (long long)T * T);
    }

    // 5) out[b,i] = [h_i | P] @ [wdown | LR*tpT]^T  (variable K = 4096 + i*256)
    if (g_big) {
        k_gemm256_out<<<dim3(256, 1, 1), 512, 98304, stream>>>(h, wdown_bf, P, tpT, out);
    } else {
        k_gemm_out<<<dim3(D / BN, C / BM, Bb * 16), 256, 0, stream>>>(
            h, wdown_bf, P, tpT, out);
    }
}

// Round 4
// 593.359 us; speedup vs baseline: 1.0596x; 1.0364x over previous
//
#include <hip/hip_runtime.h>
#include <hip/hip_bf16.h>
#include <stdint.h>

typedef unsigned short ushort_t;
typedef __bf16 bf16x8 __attribute__((ext_vector_type(8)));
typedef float f32x16 __attribute__((ext_vector_type(16)));

#define BM 128
#define BN 128
#define BK 64   // 16 KB per tile; XOR-swizzled 16B chunks

// ---------- helpers ----------
__device__ inline float b2f(ushort_t u) {
    unsigned int x = ((unsigned int)u) << 16;
    float f; __builtin_memcpy(&f, &x, 4); return f;
}
__device__ inline ushort_t f2b(float f) {
    unsigned int x; __builtin_memcpy(&x, &f, 4);
    unsigned int r = (x + 0x7FFFu + ((x >> 16) & 1u)) >> 16;
    return (ushort_t)r;
}
__device__ inline void stage16(const ushort_t* g, ushort_t* s) {
    __builtin_amdgcn_global_load_lds((const __attribute__((address_space(1))) void*)g,
                                     (__attribute__((address_space(3))) void*)s, 16, 0, 0);
}
// swizzle position function: folds row bits 3-4 so stride-8 lane groups (HW b128
// conflict granularity; inferred R5/R6 counter A/B) never exceed 2-way.
__device__ inline int swz(int r) { return (r & 7) ^ ((r >> 3) & 3); }
// stage one 128x64 bf16 tile; LDS slot e (row e>>3, pos e&7) holds global chunk (e&7)^swz(row)
__device__ inline void stage_tile(const ushort_t* G, int ld, int k0, ushort_t* S, int tid) {
#pragma unroll
    for (int t = 0; t < 4; ++t) {
        int e = tid + t * 256;
        int row = e >> 3;
        int sw = ((e & 7) ^ swz(row)) * 8;
        stage16(G + (long long)row * ld + k0 + sw, &S[e * 8]);
    }
}
__device__ inline bf16x8 ldfrag(const ushort_t* S, int r, int c) {
    return *(const bf16x8*)&S[r * BK + ((c ^ swz(r)) * 8)];
}
// XCD-aware tile decode for 128^2 kernels (B-resident mapping; good when B is small
// relative to A re-reads, e.g. k_gemm_nt).
__device__ inline void tile_decode(int& m0, int& n0) {
    const int nx = gridDim.x;
    int lin = blockIdx.y * nx + blockIdx.x;
    if ((nx & 7) == 0) {
        int q = nx >> 3;
        int k = lin & 7, s = lin >> 3;
        n0 = (k * q + s % q) * BN;
        m0 = (s / q) * BM;
    } else {
        m0 = blockIdx.y * BM;
        n0 = blockIdx.x * BN;
    }
}

// ==================== 256-wide pipelined GEMM cores ====================
// R4: restored the R2 4-phase schedule (measured best: 40% MfmaUtil) — the R3
// 2-phase merge regressed (34%). New in R4: all LDS fragment byte-offsets are
// HOISTED out of the K-loop into registers (they are loop-invariant; K-half is
// a compile-time +8192), removing the per-phase swizzle VALU from the critical
// path before each barrier.

#define SBAR() __builtin_amdgcn_sched_barrier(0)
#define BARRIER() do { SBAR(); __builtin_amdgcn_s_barrier(); SBAR(); } while (0)
#define WAITV(N) asm volatile("s_waitcnt vmcnt(" #N ")" ::: "memory")

__device__ inline int sw2(int r) { return ((r) & 3) ^ ((r >> 3) & 3); }

// stage K-half h (cols 32h..32h+31) of a 256-row tile (2 loads/thread).
// slot s=(r*4+q) -> LDS half region Sbuf + h*8192; slot holds chunk 4h + (q^sw2(r)).
__device__ inline void stage_half(const ushort_t* G, int ldg, int kElem,
                                  ushort_t* Sbuf, int h, int tid) {
#pragma unroll
    for (int i2 = 0; i2 < 2; ++i2) {
        int s = tid + i2 * 512;
        int r = s >> 2, q = s & 3;
        int c = 4 * h + (q ^ sw2(r));
        stage16(G + (long long)r * ldg + kElem + c * 8, Sbuf + h * 8192 + s * 8);
    }
}
// stage K-half h of a 128-row tile (1 load/thread); half region stride 4096 ushorts.
__device__ inline void stage_halfA(const ushort_t* G, int ldg,
                                   ushort_t* Sbuf, int h, int tid) {
    int r = tid >> 2, q = tid & 3;
    int c = 4 * h + (q ^ sw2(r));
    stage16(G + (long long)r * ldg + c * 8, Sbuf + h * 4096 + tid * 8);
}
// fragment byte-offset (in ushorts) for (row r, K-chunk c in 0..3 of a K-half)
__device__ inline int frag_off(int r, int c) {
    return r * 32 + ((c ^ sw2(r)) & 3) * 8;
}

// ---- 256x256 core (8 waves of 128x64), 4 phases per K-tile (R2 schedule) ----
template <int KS0, int MI0, bool LB>
__device__ __forceinline__ void phase_load(const ushort_t* cA, const ushort_t* cB,
                                           const int oa[4][2], const int ob[2][2],
                                           bf16x8 af_[2][2], bf16x8 bf_[2][2]) {
    constexpr int HO = (KS0 >> 1) * 8192;   // K-half 1 lives +8192 ushorts
#pragma unroll
    for (int k2 = 0; k2 < 2; ++k2) {
#pragma unroll
        for (int m2 = 0; m2 < 2; ++m2)
            af_[m2][k2] = *(const bf16x8*)&cA[oa[MI0 + m2][k2] + HO];
        if (LB) {
#pragma unroll
            for (int n2 = 0; n2 < 2; ++n2)
                bf_[n2][k2] = *(const bf16x8*)&cB[ob[n2][k2] + HO];
        }
    }
}
template <int MI0>
__device__ __forceinline__ void phase_mfma(bf16x8 af_[2][2], bf16x8 bf_[2][2],
                                           f32x16 (&acc)[4][2]) {
#pragma unroll
    for (int k2 = 0; k2 < 2; ++k2)
#pragma unroll
        for (int m2 = 0; m2 < 2; ++m2)
#pragma unroll
            for (int n2 = 0; n2 < 2; ++n2)
                acc[MI0 + m2][n2] = __builtin_amdgcn_mfma_f32_32x32x16_bf16(
                    af_[m2][k2], bf_[n2][k2], acc[MI0 + m2][n2], 0, 0, 0);
}

// requires K % 64 == 0 and K >= 128
__device__ __forceinline__ void gemm256_core(const ushort_t* __restrict__ Ag, int lda,
                                             const ushort_t* __restrict__ Bg, int ldb,
                                             int K, ushort_t* smem, int tid,
                                             int wr, int wc, int l32, int hl,
                                             f32x16 (&acc)[4][2]) {
    ushort_t* A0s = smem;
    ushort_t* A1s = smem + 16384;
    ushort_t* B0s = smem + 32768;
    ushort_t* B1s = smem + 49152;
    const int NT = K >> 6;

    // hoisted loop-invariant fragment offsets (registers; static indexing only)
    int oa[4][2], ob[2][2];
#pragma unroll
    for (int m2 = 0; m2 < 4; ++m2)
#pragma unroll
        for (int k2 = 0; k2 < 2; ++k2)
            oa[m2][k2] = frag_off(wr * 128 + m2 * 32 + l32, k2 * 2 + hl);
#pragma unroll
    for (int n2 = 0; n2 < 2; ++n2)
#pragma unroll
        for (int k2 = 0; k2 < 2; ++k2)
            ob[n2][k2] = frag_off(wc * 64 + n2 * 32 + l32, k2 * 2 + hl);

    // prologue: A0(0),B0(0),A1(0),B1(0),A0(1),B0(1) then wait for A0,B0(0)
    stage_half(Ag, lda, 0, A0s, 0, tid);
    stage_half(Bg, ldb, 0, B0s, 0, tid);
    stage_half(Ag, lda, 0, A0s, 1, tid);
    stage_half(Bg, ldb, 0, B0s, 1, tid);
    stage_half(Ag, lda, 64, A1s, 0, tid);
    stage_half(Bg, ldb, 64, B1s, 0, tid);
    WAITV(8);
    BARRIER();

    for (int kt = 0; kt < NT; ++kt) {
        ushort_t* cA = (kt & 1) ? A1s : A0s;
        ushort_t* cB = (kt & 1) ? B1s : B0s;
        ushort_t* nA = (kt & 1) ? A0s : A1s;
        ushort_t* nB = (kt & 1) ? B0s : B1s;
        const bool h1 = (kt + 1 < NT), h2 = (kt + 2 < NT);
        const int kE1 = (kt + 1) << 6, kE2 = (kt + 2) << 6;
        bf16x8 af_[2][2], bf_[2][2];
        // ---- P1: issue A1(kt+1); compute (ks 0-1, mi 0-1)
        if (h1) stage_half(Ag, lda, kE1, nA, 1, tid);
        phase_load<0, 0, true>(cA, cB, oa, ob, af_, bf_);
        BARRIER();
        __builtin_amdgcn_s_setprio(1);
        phase_mfma<0>(af_, bf_, acc);
        __builtin_amdgcn_s_setprio(0);
        BARRIER();
        // ---- P2: issue B1(kt+1); compute (ks 0-1, mi 2-3); wait for A1,B1(kt)
        if (h1) stage_half(Bg, ldb, kE1, nB, 1, tid);
        phase_load<0, 2, false>(cA, cB, oa, ob, af_, bf_);
        BARRIER();
        __builtin_amdgcn_s_setprio(1);
        phase_mfma<2>(af_, bf_, acc);
        __builtin_amdgcn_s_setprio(0);
        if (h1) { WAITV(8); } else { WAITV(0); }
        BARRIER();
        // ---- P3: issue A0(kt+2); compute (ks 2-3, mi 0-1)
        if (h2) stage_half(Ag, lda, kE2, cA, 0, tid);
        phase_load<2, 0, true>(cA, cB, oa, ob, af_, bf_);
        BARRIER();
        __builtin_amdgcn_s_setprio(1);
        phase_mfma<0>(af_, bf_, acc);
        __builtin_amdgcn_s_setprio(0);
        BARRIER();
        // ---- P4: issue B0(kt+2); compute (ks 2-3, mi 2-3); wait for A0,B0(kt+1)
        if (h2) stage_half(Bg, ldb, kE2, cB, 0, tid);
        phase_load<2, 2, false>(cA, cB, oa, ob, af_, bf_);
        BARRIER();
        __builtin_amdgcn_s_setprio(1);
        phase_mfma<2>(af_, bf_, acc);
        __builtin_amdgcn_s_setprio(0);
        if (h1) { if (h2) { WAITV(8); } else { WAITV(4); } }
        BARRIER();
    }
}

// ---- 256^2 fused gate_up GEMM + in-register SiLU (weights row-PERMUTED:
// permuted row 64q+s = gate row 32q+s (s<32) else up row 32q+s-32, so
// acc[mi][0]=gate, acc[mi][1]=up for the SAME h column). grid (32,32), 512 thr.
__global__ __launch_bounds__(512, 2)
void k_gemm256_silu(const ushort_t* __restrict__ A, const ushort_t* __restrict__ Bp,
                    ushort_t* __restrict__ H) {
    extern __shared__ __attribute__((aligned(16))) ushort_t smem2[];
    const int tid = threadIdx.x;
    const int lane = tid & 63, l32 = lane & 31, hl = lane >> 5;
    const int wv = tid >> 6, wr = wv >> 2, wc = wv & 3;
    // XCD-aware 256-tile decode: XCD k owns 4 n-tiles, sweeps m (nwg=1024, %8==0)
    int lin = blockIdx.y * 32 + blockIdx.x;
    int k8 = lin & 7, s = lin >> 3;
    int n0 = (k8 * 4 + (s & 3)) * 256;
    int m0 = (s >> 2) * 256;
    const ushort_t* Ag = A + (long long)m0 * 1024;
    const ushort_t* Bg = Bp + (long long)n0 * 1024;
    f32x16 acc[4][2];
#pragma unroll
    for (int i = 0; i < 4; ++i) { acc[i][0] = (f32x16)(0.f); acc[i][1] = (f32x16)(0.f); }
    gemm256_core(Ag, 1024, Bg, 1024, 1024, smem2, tid, wr, wc, l32, hl, acc);
    const int hc = (n0 >> 1) + wc * 32 + l32;
#pragma unroll
    for (int mi = 0; mi < 4; ++mi)
#pragma unroll
        for (int reg = 0; reg < 16; ++reg) {
            int row = m0 + wr * 128 + mi * 32 + (reg & 3) + 8 * (reg >> 2) + 4 * hl;
            float g = acc[mi][0][reg], u = acc[mi][1][reg];
            float sg = g / (1.f + __expf(-g));
            H[(long long)row * 4096 + hc] = f2b(sg * u);
        }
}

// ---- 256^2 triangular P GEMM: one block per (b,i,j) pair (exactly one 256^2
// tile). Bijective XCD remap: XCD x gets 30 consecutive pairIdx -> same-i runs
// share an XCD's L2 (h_i stays hot).
__global__ __launch_bounds__(512, 2)
void k_gemm256_tri(const ushort_t* __restrict__ Hh, ushort_t* __restrict__ P) {
    extern __shared__ __attribute__((aligned(16))) ushort_t smem2[];
    const int tid = threadIdx.x;
    const int lane = tid & 63, l32 = lane & 31, hl = lane >> 5;
    const int wv = tid >> 6, wr = wv >> 2, wc = wv & 3;
    int pairIdx = (blockIdx.x & 7) * 30 + (blockIdx.x >> 3);   // 240 = 8*30
    const int bb = pairIdx / 120;
    int p = pairIdx % 120;
    int i = 1, rem = p;
    while (rem >= i) { rem -= i; ++i; }
    const int j = rem;
    const ushort_t* Ag = Hh + (long long)bb * 4096 * 4096 + (long long)(i * 256) * 4096;
    const ushort_t* Bg = Hh + (long long)bb * 4096 * 4096 + (long long)(j * 256) * 4096;
    f32x16 acc[4][2];
#pragma unroll
    for (int a = 0; a < 4; ++a) { acc[a][0] = (f32x16)(0.f); acc[a][1] = (f32x16)(0.f); }
    gemm256_core(Ag, 4096, Bg, 4096, 4096, smem2, tid, wr, wc, l32, hl, acc);
    ushort_t* Pp = P + (long long)bb * 4096 * 4096;
#pragma unroll
    for (int mi = 0; mi < 4; ++mi)
#pragma unroll
        for (int nj = 0; nj < 2; ++nj) {
            int col = j * 256 + wc * 64 + nj * 32 + l32;
#pragma unroll
            for (int reg = 0; reg < 16; ++reg) {
                int row = i * 256 + wr * 128 + mi * 32 + (reg & 3) + 8 * (reg >> 2) + 4 * hl;
                Pp[(long long)row * 4096 + col] = f2b(acc[mi][nj][reg]);
            }
        }
}

// ==================== fused output GEMM, pipelined 128x256 ====================
// out[b,ii] = [h_ii | P_ii,0:ii*C] @ [wdown | tpT]^T, K = 4096 + ii*256.
// 256 blocks (512 thr, 8 waves of 64x64, 96 KiB LDS -> 1 block/CU, all resident).
// A-resident XCD decode: XCD x owns z in {4x..4x+3} x all 8 (m,n)-tiles.
template <int KS0>
__device__ __forceinline__ void oload_ks(const ushort_t* cA, const ushort_t* cB,
                                         const int oa[2][2], const int ob[2][2],
                                         bf16x8 af_[2][2], bf16x8 bf_[2][2]) {
    constexpr int HOA = (KS0 >> 1) * 4096;
    constexpr int HOB = (KS0 >> 1) * 8192;
#pragma unroll
    for (int k2 = 0; k2 < 2; ++k2) {
#pragma unroll
        for (int m2 = 0; m2 < 2; ++m2)
            af_[m2][k2] = *(const bf16x8*)&cA[oa[m2][k2] + HOA];
#pragma unroll
        for (int n2 = 0; n2 < 2; ++n2)
            bf_[n2][k2] = *(const bf16x8*)&cB[ob[n2][k2] + HOB];
    }
}
__device__ __forceinline__ void omfma(bf16x8 af_[2][2], bf16x8 bf_[2][2],
                                      f32x16 (&acc)[2][2]) {
#pragma unroll
    for (int k2 = 0; k2 < 2; ++k2)
#pragma unroll
        for (int m2 = 0; m2 < 2; ++m2)
#pragma unroll
            for (int n2 = 0; n2 < 2; ++n2)
                acc[m2][n2] = __builtin_amdgcn_mfma_f32_32x32x16_bf16(
                    af_[m2][k2], bf_[n2][k2], acc[m2][n2], 0, 0, 0);
}

__global__ __launch_bounds__(512, 2)
void k_gemm256_out(const ushort_t* __restrict__ h, const ushort_t* __restrict__ wdown,
                   const ushort_t* __restrict__ P, const ushort_t* __restrict__ tpT,
                   float* __restrict__ out) {
    constexpr int T = 4096, D = 1024, F = 4096, C = 256, K1 = 4096;
    extern __shared__ __attribute__((aligned(16))) ushort_t smem2[];
    const int tid = threadIdx.x;
    const int lane = tid & 63, l32 = lane & 31, hl = lane >> 5;
    const int wv = tid >> 6, wr = wv >> 2, wc = wv & 3;   // wr 0..1, wc 0..3

    // A-resident XCD decode: physical bx -> XCD = bx&7 owns logical 32-chunk.
    const int bx = blockIdx.x;
    const int logical = (bx & 7) * 32 + (bx >> 3);        // 256 blocks
    const int z = logical >> 3, t = logical & 7;          // z 0..31
    const int bb = z >> 4, ii = z & 15;
    const int m0 = (t >> 2) * 128, n0 = (t & 3) * 256;
    const int K = K1 + ii * C;

    const ushort_t* hA = h + (long long)bb * T * F + (long long)(ii * C + m0) * F;
    const ushort_t* pA = P + (long long)bb * T * T + (long long)(ii * C + m0) * T;
    const ushort_t* wB = wdown + (long long)n0 * F;
    const ushort_t* tB = tpT + (long long)bb * D * T + (long long)n0 * T;

    ushort_t* A0s = smem2;              // 8192 ushorts each (16 KB)
    ushort_t* A1s = smem2 + 8192;
    ushort_t* B0s = smem2 + 16384;      // 16384 ushorts each (32 KB)
    ushort_t* B1s = smem2 + 32768;

    // hoisted loop-invariant fragment offsets
    int oa[2][2], ob[2][2];
#pragma unroll
    for (int m2 = 0; m2 < 2; ++m2)
#pragma unroll
        for (int k2 = 0; k2 < 2; ++k2)
            oa[m2][k2] = frag_off(wr * 64 + m2 * 32 + l32, k2 * 2 + hl);
#pragma unroll
    for (int n2 = 0; n2 < 2; ++n2)
#pragma unroll
        for (int k2 = 0; k2 < 2; ++k2)
            ob[n2][k2] = frag_off(wc * 64 + n2 * 32 + l32, k2 * 2 + hl);

    f32x16 acc[2][2];
#pragma unroll
    for (int a = 0; a < 2; ++a)
#pragma unroll
        for (int c = 0; c < 2; ++c) acc[a][c] = (f32x16)(0.f);

    auto srcA = [&](int kE) { return kE < K1 ? hA + kE : pA + (kE - K1); };
    auto srcB = [&](int kE) { return kE < K1 ? wB + kE : tB + (kE - K1); };

    const int NT = K >> 6;   // >= 64

    // prologue: A(0)h0,B(0)h0,A(0)h1,B(0)h1,A(1)h0,B(1)h0  (9 loads)
    stage_halfA(srcA(0), F, A0s, 0, tid);
    stage_half (srcB(0), F, 0, B0s, 0, tid);
    stage_halfA(srcA(0), F, A0s, 1, tid);
    stage_half (srcB(0), F, 0, B0s, 1, tid);
    stage_halfA(srcA(64), F, A1s, 0, tid);
    stage_half (srcB(64), F, 0, B1s, 0, tid);
    WAITV(6);
    BARRIER();

    for (int kt = 0; kt < NT; ++kt) {
        ushort_t* cA = (kt & 1) ? A1s : A0s;
        ushort_t* cB = (kt & 1) ? B1s : B0s;
        ushort_t* nA = (kt & 1) ? A0s : A1s;
        ushort_t* nB = (kt & 1) ? B0s : B1s;
        const bool h1 = (kt + 1 < NT), h2 = (kt + 2 < NT);
        const int kE1 = (kt + 1) << 6, kE2 = (kt + 2) << 6;
        bf16x8 af_[2][2], bf_[2][2];
        // ---- PH1: issue A(kt+1)h1 + B(kt+1)h1; compute ks 0-1; wait A/B(kt)h1
        if (h1) {
            stage_halfA(srcA(kE1), F, nA, 1, tid);
            stage_half (srcB(kE1), F, 0, nB, 1, tid);
        }
        oload_ks<0>(cA, cB, oa, ob, af_, bf_);
        BARRIER();
        __builtin_amdgcn_s_setprio(1);
        omfma(af_, bf_, acc);
        __builtin_amdgcn_s_setprio(0);
        if (h1) { WAITV(6); } else { WAITV(0); }
        BARRIER();
        // ---- PH2: issue A(kt+2)h0 + B(kt+2)h0; compute ks 2-3; wait A/B(kt+1)h0
        if (h2) {
            stage_halfA(srcA(kE2), F, cA, 0, tid);
            stage_half (srcB(kE2), F, 0, cB, 0, tid);
        }
        oload_ks<2>(cA, cB, oa, ob, af_, bf_);
        BARRIER();
        __builtin_amdgcn_s_setprio(1);
        omfma(af_, bf_, acc);
        __builtin_amdgcn_s_setprio(0);
        if (h2) { WAITV(6); } else { if (h1) { WAITV(3); } else { WAITV(0); } }
        BARRIER();
    }

    float* Op = out + (long long)bb * T * D + (long long)(ii * C) * D;
#pragma unroll
    for (int mi = 0; mi < 2; ++mi)
#pragma unroll
        for (int nj = 0; nj < 2; ++nj) {
            int col = n0 + wc * 64 + nj * 32 + l32;
#pragma unroll
            for (int reg = 0; reg < 16; ++reg) {
                int row = m0 + wr * 64 + mi * 32 + (reg & 3) + 8 * (reg >> 2) + 4 * hl;
                Op[(long long)row * D + col] = acc[mi][nj][reg];
            }
        }
}

// ---------- fused prep: fp32->bf16 converts (x|wgu|proj|wdown) + causal conv ----------
// permW: write wgu in the gate/up-interleaved row order for k_gemm256_silu.
// conv: 4 consecutive t-positions per thread (window reuse: tt read 1.6x not 5x).
__global__ void k_prep(const float* __restrict__ x, const float* __restrict__ wgu,
                       const float* __restrict__ proj, const float* __restrict__ wdown,
                       const float* __restrict__ tt, const float* __restrict__ cw,
                       const float* __restrict__ cb,
                       ushort_t* __restrict__ xb, ushort_t* __restrict__ gb,
                       ushort_t* __restrict__ pb, ushort_t* __restrict__ wb,
                       ushort_t* __restrict__ tb, int permW) {
    constexpr int T = 4096, D = 1024;
    int blk = blockIdx.x;
    if (blk < 21504) {
        // converts, float4-wide: x 2097152 | wgu 2097152 | proj 262144 | wdown 1048576 units
        int i = blk * 256 + threadIdx.x;
        const float* src; ushort_t* dst; int off; int dstoff;
        if (i < 2097152)      { src = x;     dst = xb; off = i; dstoff = off; }
        else if (i < 4194304) {
            src = wgu; dst = gb; off = i - 2097152;
            if (permW) {
                int r = off >> 8, cu = off & 255;
                int pr = (r < 4096) ? (((r >> 5) << 6) + (r & 31))
                                    : ((((r - 4096) >> 5) << 6) + 32 + ((r - 4096) & 31));
                dstoff = (pr << 8) + cu;
            } else dstoff = off;
        }
        else if (i < 4456448) { src = proj;  dst = pb; off = i - 4194304; dstoff = off; }
        else                  { src = wdown; dst = wb; off = i - 4456448; dstoff = off; }
        float4 v = ((const float4*)src)[off];
        ushort4 o; o.x = f2b(v.x); o.y = f2b(v.y); o.z = f2b(v.z); o.w = f2b(v.w);
        ((ushort4*)dst)[dstoff] = o;
    } else {
        // causal depthwise conv (K=5), 4 t-positions per thread, window reuse
        int idx = (blk - 21504) * 256 + threadIdx.x;      // B*(T/4)*D threads
        int d = idx & (D - 1);
        int tq = (idx >> 10) & (T / 4 - 1);
        int b = idx / (D * (T / 4));
        int t0 = tq * 4;
        const float* base = tt + (long long)b * T * D + d;
        float w0 = cw[d * 5 + 0], w1 = cw[d * 5 + 1], w2 = cw[d * 5 + 2],
              w3 = cw[d * 5 + 3], w4 = cw[d * 5 + 4];
        float bias = cb[d];
        float win[8];
#pragma unroll
        for (int m = 0; m < 8; ++m) {
            int ts = t0 - 4 + m;
            win[m] = (ts >= 0) ? base[(long long)ts * D] : 0.f;
        }
        ushort_t* op = tb + (long long)b * T * D + (long long)t0 * D + d;
#pragma unroll
        for (int r = 0; r < 4; ++r) {
            float a = bias + w0 * win[r] + w1 * win[r + 1] + w2 * win[r + 2]
                    + w3 * win[r + 3] + w4 * win[r + 4];
            op[(long long)r * D] = f2b(a);
        }
    }
}

// ---------- batched bf16 NT GEMM (bf16 out): C[m,n] = scale * sum_k A[m,k]*B[n,k] ----------
__global__ __launch_bounds__(256, 4)
void k_gemm_nt(const ushort_t* __restrict__ A, const ushort_t* __restrict__ B,
               ushort_t* __restrict__ C, int K, int lda, int ldb, int ldc,
               long long sAb, long long sBb, long long sCb, float scale) {
    __shared__ __attribute__((aligned(16))) ushort_t sA[BM * BK];
    __shared__ __attribute__((aligned(16))) ushort_t sB[BN * BK];

    int m0, n0;
    tile_decode(m0, n0);
    const int bb = blockIdx.z;
    const ushort_t* Ab = A + bb * sAb + (long long)m0 * lda;
    const ushort_t* Bb = B + bb * sBb + (long long)n0 * ldb;

    const int tid = threadIdx.x;
    const int lane = tid & 63, l32 = lane & 31, half = lane >> 5;
    const int wave = tid >> 6;
    const int wm = (wave >> 1) * 64, wn = (wave & 1) * 64;

    f32x16 acc[2][2];
#pragma unroll
    for (int i = 0; i < 2; ++i)
#pragma unroll
        for (int j = 0; j < 2; ++j) acc[i][j] = (f32x16)(0.f);

    for (int k0 = 0; k0 < K; k0 += BK) {
        __syncthreads();
        stage_tile(Ab, lda, k0, sA, tid);
        stage_tile(Bb, ldb, k0, sB, tid);
        __syncthreads();
#pragma unroll
        for (int ks = 0; ks < 4; ++ks) {
            bf16x8 af[2], bfr[2];
#pragma unroll
            for (int mi = 0; mi < 2; ++mi)
                af[mi] = ldfrag(sA, wm + mi * 32 + l32, ks * 2 + half);
#pragma unroll
            for (int nj = 0; nj < 2; ++nj)
                bfr[nj] = ldfrag(sB, wn + nj * 32 + l32, ks * 2 + half);
#pragma unroll
            for (int mi = 0; mi < 2; ++mi)
#pragma unroll
                for (int nj = 0; nj < 2; ++nj)
                    acc[mi][nj] = __builtin_amdgcn_mfma_f32_32x32x16_bf16(af[mi], bfr[nj], acc[mi][nj], 0, 0, 0);
        }
    }

    ushort_t* Cp = C + bb * sCb;
#pragma unroll
    for (int mi = 0; mi < 2; ++mi)
#pragma unroll
        for (int nj = 0; nj < 2; ++nj) {
            int col = n0 + wn + nj * 32 + l32;
#pragma unroll
            for (int reg = 0; reg < 16; ++reg) {
                int row = m0 + wm + mi * 32 + (reg & 3) + 8 * (reg >> 2) + 4 * half;
                Cp[(long long)row * ldc + col] = f2b(acc[mi][nj][reg] * scale);
            }
        }
}

// ---------- fallback fused gate_up GEMM + SiLU (unpermuted weights) ----------
__global__ __launch_bounds__(256)
void k_gemm_silu(const ushort_t* __restrict__ A, const ushort_t* __restrict__ Bg,
                 const ushort_t* __restrict__ Bu, ushort_t* __restrict__ H,
                 int K, int lda, int ldb, int ldh) {
    __shared__ __attribute__((aligned(16))) ushort_t sA[BM * BK];
    __shared__ __attribute__((aligned(16))) ushort_t sBg[BN * BK];
    __shared__ __attribute__((aligned(16))) ushort_t sBu[BN * BK];

    int m0, n0;
    tile_decode(m0, n0);
    const ushort_t* Ab = A + (long long)m0 * lda;
    const ushort_t* Bgb = Bg + (long long)n0 * ldb;
    const ushort_t* Bub = Bu + (long long)n0 * ldb;

    const int tid = threadIdx.x;
    const int lane = tid & 63, l32 = lane & 31, half = lane >> 5;
    const int wave = tid >> 6;
    const int wm = (wave >> 1) * 64, wn = (wave & 1) * 64;

    f32x16 ag[2][2], au[2][2];
#pragma unroll
    for (int i = 0; i < 2; ++i)
#pragma unroll
        for (int j = 0; j < 2; ++j) { ag[i][j] = (f32x16)(0.f); au[i][j] = (f32x16)(0.f); }

    for (int k0 = 0; k0 < K; k0 += BK) {
        __syncthreads();
        stage_tile(Ab, lda, k0, sA, tid);
        stage_tile(Bgb, ldb, k0, sBg, tid);
        stage_tile(Bub, ldb, k0, sBu, tid);
        __syncthreads();
#pragma unroll
        for (int ks = 0; ks < 4; ++ks) {
            bf16x8 af[2], bg[2], bu[2];
#pragma unroll
            for (int mi = 0; mi < 2; ++mi)
                af[mi] = ldfrag(sA, wm + mi * 32 + l32, ks * 2 + half);
#pragma unroll
            for (int nj = 0; nj < 2; ++nj) {
                bg[nj] = ldfrag(sBg, wn + nj * 32 + l32, ks * 2 + half);
                bu[nj] = ldfrag(sBu, wn + nj * 32 + l32, ks * 2 + half);
            }
#pragma unroll
            for (int mi = 0; mi < 2; ++mi)
#pragma unroll
                for (int nj = 0; nj < 2; ++nj) {
                    ag[mi][nj] = __builtin_amdgcn_mfma_f32_32x32x16_bf16(af[mi], bg[nj], ag[mi][nj], 0, 0, 0);
                    au[mi][nj] = __builtin_amdgcn_mfma_f32_32x32x16_bf16(af[mi], bu[nj], au[mi][nj], 0, 0, 0);
                }
        }
    }

#pragma unroll
    for (int mi = 0; mi < 2; ++mi)
#pragma unroll
        for (int nj = 0; nj < 2; ++nj) {
            int col = n0 + wn + nj * 32 + l32;
#pragma unroll
            for (int reg = 0; reg < 16; ++reg) {
                int row = m0 + wm + mi * 32 + (reg & 3) + 8 * (reg >> 2) + 4 * half;
                float g = ag[mi][nj][reg], u = au[mi][nj][reg];
                float s = g / (1.f + __expf(-g));
                H[(long long)row * ldh + col] = f2b(s * u);
            }
        }
}

// ---------- fallback triangular P GEMM (128^2 tiles) ----------
__global__ __launch_bounds__(256, 4)
void k_gemm_tri(const ushort_t* __restrict__ H, ushort_t* __restrict__ P,
                int K, int ldh, int ldp, long long sHb, long long sPb) {
    __shared__ __attribute__((aligned(16))) ushort_t sA[BM * BK];
    __shared__ __attribute__((aligned(16))) ushort_t sB[BN * BK];

    const int lin = blockIdx.x;
    const int g = lin >> 5, w = lin & 31;
    const int xk = w & 7, t = w >> 3;
    int pairIdx = g * 8 + xk;            // 0..239
    const int bb = pairIdx / 120;
    int p = pairIdx % 120;
    int i = 1, rem = p;
    while (rem >= i) { rem -= i; ++i; }
    const int j = rem;
    const int m0 = (t >> 1) * BM, n0 = (t & 1) * BN;

    const ushort_t* Ab = H + bb * sHb + (long long)(i * 256 + m0) * ldh;
    const ushort_t* Bb = H + bb * sHb + (long long)(j * 256 + n0) * ldh;

    const int tid = threadIdx.x;
    const int lane = tid & 63, l32 = lane & 31, half = lane >> 5;
    const int wave = tid >> 6;
    const int wm = (wave >> 1) * 64, wn = (wave & 1) * 64;

    f32x16 acc[2][2];
#pragma unroll
    for (int a = 0; a < 2; ++a)
#pragma unroll
        for (int c = 0; c < 2; ++c) acc[a][c] = (f32x16)(0.f);

    for (int k0 = 0; k0 < K; k0 += BK) {
        __syncthreads();
        stage_tile(Ab, ldh, k0, sA, tid);
        stage_tile(Bb, ldh, k0, sB, tid);
        __syncthreads();
#pragma unroll
        for (int ks = 0; ks < 4; ++ks) {
            bf16x8 af[2], bfr[2];
#pragma unroll
            for (int mi = 0; mi < 2; ++mi)
                af[mi] = ldfrag(sA, wm + mi * 32 + l32, ks * 2 + half);
#pragma unroll
            for (int nj = 0; nj < 2; ++nj)
                bfr[nj] = ldfrag(sB, wn + nj * 32 + l32, ks * 2 + half);
#pragma unroll
            for (int mi = 0; mi < 2; ++mi)
#pragma unroll
                for (int nj = 0; nj < 2; ++nj)
                    acc[mi][nj] = __builtin_amdgcn_mfma_f32_32x32x16_bf16(af[mi], bfr[nj], acc[mi][nj], 0, 0, 0);
        }
    }

    ushort_t* Pp = P + bb * sPb;
#pragma unroll
    for (int mi = 0; mi < 2; ++mi)
#pragma unroll
        for (int nj = 0; nj < 2; ++nj) {
            int col = j * 256 + n0 + wn + nj * 32 + l32;
#pragma unroll
            for (int reg = 0; reg < 16; ++reg) {
                int row = i * 256 + m0 + wm + mi * 32 + (reg & 3) + 8 * (reg >> 2) + 4 * half;
                Pp[(long long)row * ldp + col] = f2b(acc[mi][nj][reg]);
            }
        }
}

// ---------- fallback fused output GEMM (128^2) ----------
__global__ __launch_bounds__(256, 4)
void k_gemm_out(const ushort_t* __restrict__ h, const ushort_t* __restrict__ wdown,
                const ushort_t* __restrict__ P, const ushort_t* __restrict__ tpT,
                float* __restrict__ out) {
    constexpr int T = 4096, D = 1024, F = 4096, C = 256, K1 = 4096;
    __shared__ __attribute__((aligned(16))) ushort_t sA[BM * BK];
    __shared__ __attribute__((aligned(16))) ushort_t sB[BN * BK];

    const int z = blockIdx.z, bb = z >> 4, ii = z & 15;
    const int K2 = ii * C;
    int m0, n0;
    tile_decode(m0, n0);

    const ushort_t* A1 = h + (long long)bb * T * F + (long long)(ii * C + m0) * F;
    const ushort_t* B1 = wdown + (long long)n0 * F;
    const ushort_t* A2 = P + (long long)bb * T * T + (long long)(ii * C + m0) * T;
    const ushort_t* B2 = tpT + (long long)bb * D * T + (long long)n0 * T;

    const int tid = threadIdx.x;
    const int lane = tid & 63, l32 = lane & 31, half = lane >> 5;
    const int wave = tid >> 6;
    const int wm = (wave >> 1) * 64, wn = (wave & 1) * 64;

    f32x16 acc[2][2];
#pragma unroll
    for (int i = 0; i < 2; ++i)
#pragma unroll
        for (int j = 0; j < 2; ++j) acc[i][j] = (f32x16)(0.f);

    const int K = K1 + K2;
    for (int k0 = 0; k0 < K; k0 += BK) {
        const ushort_t* As = (k0 < K1) ? A1 + k0 : A2 + (k0 - K1);
        const ushort_t* Bs = (k0 < K1) ? B1 + k0 : B2 + (k0 - K1);
        __syncthreads();
        stage_tile(As, 4096, 0, sA, tid);
        stage_tile(Bs, 4096, 0, sB, tid);
        __syncthreads();
#pragma unroll
        for (int ks = 0; ks < 4; ++ks) {
            bf16x8 af[2], bfr[2];
#pragma unroll
            for (int mi = 0; mi < 2; ++mi)
                af[mi] = ldfrag(sA, wm + mi * 32 + l32, ks * 2 + half);
#pragma unroll
            for (int nj = 0; nj < 2; ++nj)
                bfr[nj] = ldfrag(sB, wn + nj * 32 + l32, ks * 2 + half);
#pragma unroll
            for (int mi = 0; mi < 2; ++mi)
#pragma unroll
                for (int nj = 0; nj < 2; ++nj)
                    acc[mi][nj] = __builtin_amdgcn_mfma_f32_32x32x16_bf16(af[mi], bfr[nj], acc[mi][nj], 0, 0, 0);
        }
    }

    float* Op = out + (long long)bb * T * D + (long long)ii * C * D;
#pragma unroll
    for (int mi = 0; mi < 2; ++mi)
#pragma unroll
        for (int nj = 0; nj < 2; ++nj) {
            int col = n0 + wn + nj * 32 + l32;
#pragma unroll
            for (int reg = 0; reg < 16; ++reg) {
                int row = m0 + wm + mi * 32 + (reg & 3) + 8 * (reg >> 2) + 4 * half;
                Op[(long long)row * D + col] = acc[mi][nj][reg];
            }
        }
}

// ---------- launch ----------
static int g_big = -1;

extern "C" void kernel_launch(void* const* d_in, const int* in_sizes, int n_in,
                              void* d_out, int out_size, void* d_ws, size_t ws_size,
                              hipStream_t stream) {
    const float* x         = (const float*)d_in[0];
    const float* ttt_tgt   = (const float*)d_in[1];
    const float* w_gate_up = (const float*)d_in[2];
    const float* w_down    = (const float*)d_in[3];
    const float* ttt_proj  = (const float*)d_in[4];
    const float* conv_w    = (const float*)d_in[5];
    const float* conv_b    = (const float*)d_in[6];
    float* out = (float*)d_out;
    (void)in_sizes; (void)n_in; (void)out_size; (void)ws_size;

    constexpr int Bb = 2, T = 4096, D = 1024, F = 4096, C = 256;
    constexpr float LR = 0.01f;

    // one-time: opt in to big dynamic LDS for the pipelined kernels; if the
    // runtime refuses, fall back to the 128^2 path (status-quo performance).
    if (g_big < 0) {
        hipError_t e1 = hipFuncSetAttribute((const void*)k_gemm256_silu,
                                            hipFuncAttributeMaxDynamicSharedMemorySize, 131072);
        hipError_t e2 = hipFuncSetAttribute((const void*)k_gemm256_tri,
                                            hipFuncAttributeMaxDynamicSharedMemorySize, 131072);
        hipError_t e3 = hipFuncSetAttribute((const void*)k_gemm256_out,
                                            hipFuncAttributeMaxDynamicSharedMemorySize, 98304);
        g_big = (e1 == hipSuccess && e2 == hipSuccess && e3 == hipSuccess) ? 1 : 0;
    }

    // workspace (154 MB):
    //   [0,64M): x_bf(16M) | wgu_bf(16M) | t_bf(16M) | scratch  -> later aliased by P (B,T,T) bf16
    //   [64M..): proj_bf 2M | wdown_bf 8M | tpT 16M | h 64M
    char* ws = (char*)d_ws;
    ushort_t* x_bf     = (ushort_t*)(ws);
    ushort_t* wgu_bf   = (ushort_t*)(ws + 16777216LL);
    ushort_t* t_bf     = (ushort_t*)(ws + 2 * 16777216LL);
    ushort_t* P        = (ushort_t*)(ws);
    ushort_t* proj_bf  = (ushort_t*)(ws + 67108864LL);
    ushort_t* wdown_bf = (ushort_t*)(ws + 67108864LL + 2097152LL);
    ushort_t* tpT      = (ushort_t*)(ws + 67108864LL + 2097152LL + 8388608LL);
    ushort_t* h        = (ushort_t*)(ws + 67108864LL + 2097152LL + 8388608LL + 16777216LL);

    // 1) fused prep: converts (+ optional gate/up row interleave) + causal conv
    //    conv now 4 outputs/thread: 21504 cvt blocks + 8192 conv blocks
    k_prep<<<21504 + 8192, 256, 0, stream>>>(x, w_gate_up, ttt_proj, w_down,
                                             ttt_tgt, conv_w, conv_b,
                                             x_bf, wgu_bf, proj_bf, wdown_bf, t_bf, g_big);

    // 2) tpT[b] = LR * (proj @ t[b]^T) : M=D, N=T, K=D -> bf16 (B,D,T)
    k_gemm_nt<<<dim3(T / BN, D / BM, Bb), 256, 0, stream>>>(
        proj_bf, t_bf, tpT, D, D, D, T,
        0, (long long)T * D, (long long)D * T, LR);

    // 3) h = silu(x@Wg^T)*(x@Wu^T) : M=B*T=8192, N(permuted)=8192, K=1024
    if (g_big) {
        k_gemm256_silu<<<dim3(32, 32, 1), 512, 131072, stream>>>(x_bf, wgu_bf, h);
    } else {
        k_gemm_silu<<<dim3(F / BN, (Bb * T) / BM, 1), 256, 0, stream>>>(
            x_bf, wgu_bf, wgu_bf + (long long)F * D, h, D, D, D, F);
    }

    // 4) P lower chunk-blocks: P[b, i*C.., j*C..] = h_i h_j^T, j<i
    if (g_big) {
        k_gemm256_tri<<<dim3(240, 1, 1), 512, 131072, stream>>>(h, P);
    } else {
        k_gemm_tri<<<dim3(960, 1, 1), 256, 0, stream>>>(
            h, P, F, F, T, (long long)T * F, (long long)T * T);
    }

    // 5) out[b,i] = [h_i | P] @ [wdown | LR*tpT]^T  (variable K = 4096 + i*256)
    if (g_big) {
        k_gemm256_out<<<dim3(256, 1, 1), 512, 98304, stream>>>(h, wdown_bf, P, tpT, out);
    } else {
        k_gemm_out<<<dim3(D / BN, C / BM, Bb * 16), 256, 0, stream>>>(
            h, wdown_bf, P, tpT, out);
    }
}

// Round 5
// 551.566 us; speedup vs baseline: 1.1399x; 1.0758x over previous
//
#include <hip/hip_runtime.h>
#include <hip/hip_bf16.h>
#include <stdint.h>

typedef unsigned short ushort_t;
typedef __bf16 bf16x8 __attribute__((ext_vector_type(8)));
typedef float f32x16 __attribute__((ext_vector_type(16)));

#define BM 128
#define BN 128
#define BK 64   // 16 KB per tile; XOR-swizzled 16B chunks

// ---------- helpers ----------
__device__ inline float b2f(ushort_t u) {
    unsigned int x = ((unsigned int)u) << 16;
    float f; __builtin_memcpy(&f, &x, 4); return f;
}
__device__ inline ushort_t f2b(float f) {
    unsigned int x; __builtin_memcpy(&x, &f, 4);
    unsigned int r = (x + 0x7FFFu + ((x >> 16) & 1u)) >> 16;
    return (ushort_t)r;
}
__device__ inline void stage16(const ushort_t* g, ushort_t* s) {
    __builtin_amdgcn_global_load_lds((const __attribute__((address_space(1))) void*)g,
                                     (__attribute__((address_space(3))) void*)s, 16, 0, 0);
}
// swizzle position function: folds row bits 3-4 so stride-8 lane groups (HW b128
// conflict granularity; inferred R5/R6 counter A/B) never exceed 2-way.
__device__ inline int swz(int r) { return (r & 7) ^ ((r >> 3) & 3); }
// stage one 128x64 bf16 tile; LDS slot e (row e>>3, pos e&7) holds global chunk (e&7)^swz(row)
__device__ inline void stage_tile(const ushort_t* G, int ld, int k0, ushort_t* S, int tid) {
#pragma unroll
    for (int t = 0; t < 4; ++t) {
        int e = tid + t * 256;
        int row = e >> 3;
        int sw = ((e & 7) ^ swz(row)) * 8;
        stage16(G + (long long)row * ld + k0 + sw, &S[e * 8]);
    }
}
__device__ inline bf16x8 ldfrag(const ushort_t* S, int r, int c) {
    return *(const bf16x8*)&S[r * BK + ((c ^ swz(r)) * 8)];
}
// XCD-aware tile decode for 128^2 kernels (B-resident mapping; good when B is small
// relative to A re-reads, e.g. k_gemm_nt).
__device__ inline void tile_decode(int& m0, int& n0) {
    const int nx = gridDim.x;
    int lin = blockIdx.y * nx + blockIdx.x;
    if ((nx & 7) == 0) {
        int q = nx >> 3;
        int k = lin & 7, s = lin >> 3;
        n0 = (k * q + s % q) * BN;
        m0 = (s / q) * BM;
    } else {
        m0 = blockIdx.y * BM;
        n0 = blockIdx.x * BN;
    }
}

// ==================== 256-wide pipelined GEMM cores ====================
// R5: single-barrier phases. The R2/R4 schedule had a barrier BETWEEN the LDS
// read burst and the MFMA cluster, forcing all 8 waves to read in lockstep
// (LDS saturated, MFMA idle) then MFMA in lockstep (LDS idle). Per K-tile the
// block issues 192KB of ds_read (~768cy at 256B/clk) vs 516cy of MFMA -> LDS
// BW is the binding pipe; overlap requires wave skew. Removing the mid-phase
// barrier (keeping one barrier at phase end, after MFMA + counted WAITV) lets
// one wave's reads run under another's MFMAs. Hazards: reads of a phase are
// consumed (lgkmcnt) before its end barrier; every gload_lds targeting region
// X issues after the barrier following the last read of X. vmcnt ledger
// unchanged (same cadence, same WAITV points).

#define SBAR() __builtin_amdgcn_sched_barrier(0)
#define BARRIER() do { SBAR(); __builtin_amdgcn_s_barrier(); SBAR(); } while (0)
#define WAITV(N) asm volatile("s_waitcnt vmcnt(" #N ")" ::: "memory")

__device__ inline int sw2(int r) { return ((r) & 3) ^ ((r >> 3) & 3); }

// stage K-half h (cols 32h..32h+31) of a 256-row tile (2 loads/thread).
// slot s=(r*4+q) -> LDS half region Sbuf + h*8192; slot holds chunk 4h + (q^sw2(r)).
__device__ inline void stage_half(const ushort_t* G, int ldg, int kElem,
                                  ushort_t* Sbuf, int h, int tid) {
#pragma unroll
    for (int i2 = 0; i2 < 2; ++i2) {
        int s = tid + i2 * 512;
        int r = s >> 2, q = s & 3;
        int c = 4 * h + (q ^ sw2(r));
        stage16(G + (long long)r * ldg + kElem + c * 8, Sbuf + h * 8192 + s * 8);
    }
}
// stage K-half h of a 128-row tile (1 load/thread); half region stride 4096 ushorts.
__device__ inline void stage_halfA(const ushort_t* G, int ldg,
                                   ushort_t* Sbuf, int h, int tid) {
    int r = tid >> 2, q = tid & 3;
    int c = 4 * h + (q ^ sw2(r));
    stage16(G + (long long)r * ldg + c * 8, Sbuf + h * 4096 + tid * 8);
}
// fragment byte-offset (in ushorts) for (row r, K-chunk c in 0..3 of a K-half)
__device__ inline int frag_off(int r, int c) {
    return r * 32 + ((c ^ sw2(r)) & 3) * 8;
}

// ---- 256x256 core (8 waves of 128x64), 4 phases/K-tile, 1 barrier/phase ----
template <int KS0, int MI0, bool LB>
__device__ __forceinline__ void phase_load(const ushort_t* cA, const ushort_t* cB,
                                           const int oa[4][2], const int ob[2][2],
                                           bf16x8 af_[2][2], bf16x8 bf_[2][2]) {
    constexpr int HO = (KS0 >> 1) * 8192;   // K-half 1 lives +8192 ushorts
#pragma unroll
    for (int k2 = 0; k2 < 2; ++k2) {
#pragma unroll
        for (int m2 = 0; m2 < 2; ++m2)
            af_[m2][k2] = *(const bf16x8*)&cA[oa[MI0 + m2][k2] + HO];
        if (LB) {
#pragma unroll
            for (int n2 = 0; n2 < 2; ++n2)
                bf_[n2][k2] = *(const bf16x8*)&cB[ob[n2][k2] + HO];
        }
    }
}
template <int MI0>
__device__ __forceinline__ void phase_mfma(bf16x8 af_[2][2], bf16x8 bf_[2][2],
                                           f32x16 (&acc)[4][2]) {
#pragma unroll
    for (int k2 = 0; k2 < 2; ++k2)
#pragma unroll
        for (int m2 = 0; m2 < 2; ++m2)
#pragma unroll
            for (int n2 = 0; n2 < 2; ++n2)
                acc[MI0 + m2][n2] = __builtin_amdgcn_mfma_f32_32x32x16_bf16(
                    af_[m2][k2], bf_[n2][k2], acc[MI0 + m2][n2], 0, 0, 0);
}

// requires K % 64 == 0 and K >= 128
__device__ __forceinline__ void gemm256_core(const ushort_t* __restrict__ Ag, int lda,
                                             const ushort_t* __restrict__ Bg, int ldb,
                                             int K, ushort_t* smem, int tid,
                                             int wr, int wc, int l32, int hl,
                                             f32x16 (&acc)[4][2]) {
    ushort_t* A0s = smem;
    ushort_t* A1s = smem + 16384;
    ushort_t* B0s = smem + 32768;
    ushort_t* B1s = smem + 49152;
    const int NT = K >> 6;

    // hoisted loop-invariant fragment offsets (registers; static indexing only)
    int oa[4][2], ob[2][2];
#pragma unroll
    for (int m2 = 0; m2 < 4; ++m2)
#pragma unroll
        for (int k2 = 0; k2 < 2; ++k2)
            oa[m2][k2] = frag_off(wr * 128 + m2 * 32 + l32, k2 * 2 + hl);
#pragma unroll
    for (int n2 = 0; n2 < 2; ++n2)
#pragma unroll
        for (int k2 = 0; k2 < 2; ++k2)
            ob[n2][k2] = frag_off(wc * 64 + n2 * 32 + l32, k2 * 2 + hl);

    // prologue: A0(0),B0(0),A1(0),B1(0),A0(1),B0(1) then wait for A0,B0(0)
    stage_half(Ag, lda, 0, A0s, 0, tid);
    stage_half(Bg, ldb, 0, B0s, 0, tid);
    stage_half(Ag, lda, 0, A0s, 1, tid);
    stage_half(Bg, ldb, 0, B0s, 1, tid);
    stage_half(Ag, lda, 64, A1s, 0, tid);
    stage_half(Bg, ldb, 64, B1s, 0, tid);
    WAITV(8);
    BARRIER();

    for (int kt = 0; kt < NT; ++kt) {
        ushort_t* cA = (kt & 1) ? A1s : A0s;
        ushort_t* cB = (kt & 1) ? B1s : B0s;
        ushort_t* nA = (kt & 1) ? A0s : A1s;
        ushort_t* nB = (kt & 1) ? B0s : B1s;
        const bool h1 = (kt + 1 < NT), h2 = (kt + 2 < NT);
        const int kE1 = (kt + 1) << 6, kE2 = (kt + 2) << 6;
        bf16x8 af_[2][2], bf_[2][2];
        // ---- P1: issue A1(kt+1); read+MFMA (ks 0-1, mi 0-1)
        if (h1) stage_half(Ag, lda, kE1, nA, 1, tid);
        phase_load<0, 0, true>(cA, cB, oa, ob, af_, bf_);
        __builtin_amdgcn_s_setprio(1);
        phase_mfma<0>(af_, bf_, acc);
        __builtin_amdgcn_s_setprio(0);
        BARRIER();
        // ---- P2: issue B1(kt+1); read+MFMA (ks 0-1, mi 2-3); wait A1,B1(kt)
        if (h1) stage_half(Bg, ldb, kE1, nB, 1, tid);
        phase_load<0, 2, false>(cA, cB, oa, ob, af_, bf_);
        __builtin_amdgcn_s_setprio(1);
        phase_mfma<2>(af_, bf_, acc);
        __builtin_amdgcn_s_setprio(0);
        if (h1) { WAITV(8); } else { WAITV(0); }
        BARRIER();
        // ---- P3: issue A0(kt+2); read+MFMA (ks 2-3, mi 0-1)
        if (h2) stage_half(Ag, lda, kE2, cA, 0, tid);
        phase_load<2, 0, true>(cA, cB, oa, ob, af_, bf_);
        __builtin_amdgcn_s_setprio(1);
        phase_mfma<0>(af_, bf_, acc);
        __builtin_amdgcn_s_setprio(0);
        BARRIER();
        // ---- P4: issue B0(kt+2); read+MFMA (ks 2-3, mi 2-3); wait A0,B0(kt+1)
        if (h2) stage_half(Bg, ldb, kE2, cB, 0, tid);
        phase_load<2, 2, false>(cA, cB, oa, ob, af_, bf_);
        __builtin_amdgcn_s_setprio(1);
        phase_mfma<2>(af_, bf_, acc);
        __builtin_amdgcn_s_setprio(0);
        if (h1) { if (h2) { WAITV(8); } else { WAITV(4); } }
        BARRIER();
    }
}

// ---- 256^2 fused gate_up GEMM + in-register SiLU (weights row-PERMUTED:
// permuted row 64q+s = gate row 32q+s (s<32) else up row 32q+s-32, so
// acc[mi][0]=gate, acc[mi][1]=up for the SAME h column). grid (32,32), 512 thr.
__global__ __launch_bounds__(512, 2)
void k_gemm256_silu(const ushort_t* __restrict__ A, const ushort_t* __restrict__ Bp,
                    ushort_t* __restrict__ H) {
    extern __shared__ __attribute__((aligned(16))) ushort_t smem2[];
    const int tid = threadIdx.x;
    const int lane = tid & 63, l32 = lane & 31, hl = lane >> 5;
    const int wv = tid >> 6, wr = wv >> 2, wc = wv & 3;
    // XCD-aware 256-tile decode: XCD k owns 4 n-tiles, sweeps m (nwg=1024, %8==0)
    int lin = blockIdx.y * 32 + blockIdx.x;
    int k8 = lin & 7, s = lin >> 3;
    int n0 = (k8 * 4 + (s & 3)) * 256;
    int m0 = (s >> 2) * 256;
    const ushort_t* Ag = A + (long long)m0 * 1024;
    const ushort_t* Bg = Bp + (long long)n0 * 1024;
    f32x16 acc[4][2];
#pragma unroll
    for (int i = 0; i < 4; ++i) { acc[i][0] = (f32x16)(0.f); acc[i][1] = (f32x16)(0.f); }
    gemm256_core(Ag, 1024, Bg, 1024, 1024, smem2, tid, wr, wc, l32, hl, acc);
    const int hc = (n0 >> 1) + wc * 32 + l32;
#pragma unroll
    for (int mi = 0; mi < 4; ++mi)
#pragma unroll
        for (int reg = 0; reg < 16; ++reg) {
            int row = m0 + wr * 128 + mi * 32 + (reg & 3) + 8 * (reg >> 2) + 4 * hl;
            float g = acc[mi][0][reg], u = acc[mi][1][reg];
            float sg = g / (1.f + __expf(-g));
            H[(long long)row * 4096 + hc] = f2b(sg * u);
        }
}

// ---- 256^2 triangular P GEMM: one block per (b,i,j) pair (exactly one 256^2
// tile). Bijective XCD remap: XCD x gets 30 consecutive pairIdx -> same-i runs
// share an XCD's L2 (h_i stays hot).
__global__ __launch_bounds__(512, 2)
void k_gemm256_tri(const ushort_t* __restrict__ Hh, ushort_t* __restrict__ P) {
    extern __shared__ __attribute__((aligned(16))) ushort_t smem2[];
    const int tid = threadIdx.x;
    const int lane = tid & 63, l32 = lane & 31, hl = lane >> 5;
    const int wv = tid >> 6, wr = wv >> 2, wc = wv & 3;
    int pairIdx = (blockIdx.x & 7) * 30 + (blockIdx.x >> 3);   // 240 = 8*30
    const int bb = pairIdx / 120;
    int p = pairIdx % 120;
    int i = 1, rem = p;
    while (rem >= i) { rem -= i; ++i; }
    const int j = rem;
    const ushort_t* Ag = Hh + (long long)bb * 4096 * 4096 + (long long)(i * 256) * 4096;
    const ushort_t* Bg = Hh + (long long)bb * 4096 * 4096 + (long long)(j * 256) * 4096;
    f32x16 acc[4][2];
#pragma unroll
    for (int a = 0; a < 4; ++a) { acc[a][0] = (f32x16)(0.f); acc[a][1] = (f32x16)(0.f); }
    gemm256_core(Ag, 4096, Bg, 4096, 4096, smem2, tid, wr, wc, l32, hl, acc);
    ushort_t* Pp = P + (long long)bb * 4096 * 4096;
#pragma unroll
    for (int mi = 0; mi < 4; ++mi)
#pragma unroll
        for (int nj = 0; nj < 2; ++nj) {
            int col = j * 256 + wc * 64 + nj * 32 + l32;
#pragma unroll
            for (int reg = 0; reg < 16; ++reg) {
                int row = i * 256 + wr * 128 + mi * 32 + (reg & 3) + 8 * (reg >> 2) + 4 * hl;
                Pp[(long long)row * 4096 + col] = f2b(acc[mi][nj][reg]);
            }
        }
}

// ==================== fused output GEMM, pipelined 128x256 ====================
// out[b,ii] = [h_ii | P_ii,0:ii*C] @ [wdown | tpT]^T, K = 4096 + ii*256.
// 256 blocks (512 thr, 8 waves of 64x64, 96 KiB LDS -> 1 block/CU, all resident).
// A-resident XCD decode: XCD x owns z in {4x..4x+3} x all 8 (m,n)-tiles.
template <int KS0>
__device__ __forceinline__ void oload_ks(const ushort_t* cA, const ushort_t* cB,
                                         const int oa[2][2], const int ob[2][2],
                                         bf16x8 af_[2][2], bf16x8 bf_[2][2]) {
    constexpr int HOA = (KS0 >> 1) * 4096;
    constexpr int HOB = (KS0 >> 1) * 8192;
#pragma unroll
    for (int k2 = 0; k2 < 2; ++k2) {
#pragma unroll
        for (int m2 = 0; m2 < 2; ++m2)
            af_[m2][k2] = *(const bf16x8*)&cA[oa[m2][k2] + HOA];
#pragma unroll
        for (int n2 = 0; n2 < 2; ++n2)
            bf_[n2][k2] = *(const bf16x8*)&cB[ob[n2][k2] + HOB];
    }
}
__device__ __forceinline__ void omfma(bf16x8 af_[2][2], bf16x8 bf_[2][2],
                                      f32x16 (&acc)[2][2]) {
#pragma unroll
    for (int k2 = 0; k2 < 2; ++k2)
#pragma unroll
        for (int m2 = 0; m2 < 2; ++m2)
#pragma unroll
            for (int n2 = 0; n2 < 2; ++n2)
                acc[m2][n2] = __builtin_amdgcn_mfma_f32_32x32x16_bf16(
                    af_[m2][k2], bf_[n2][k2], acc[m2][n2], 0, 0, 0);
}

__global__ __launch_bounds__(512, 2)
void k_gemm256_out(const ushort_t* __restrict__ h, const ushort_t* __restrict__ wdown,
                   const ushort_t* __restrict__ P, const ushort_t* __restrict__ tpT,
                   float* __restrict__ out) {
    constexpr int T = 4096, D = 1024, F = 4096, C = 256, K1 = 4096;
    extern __shared__ __attribute__((aligned(16))) ushort_t smem2[];
    const int tid = threadIdx.x;
    const int lane = tid & 63, l32 = lane & 31, hl = lane >> 5;
    const int wv = tid >> 6, wr = wv >> 2, wc = wv & 3;   // wr 0..1, wc 0..3

    // A-resident XCD decode: physical bx -> XCD = bx&7 owns logical 32-chunk.
    const int bx = blockIdx.x;
    const int logical = (bx & 7) * 32 + (bx >> 3);        // 256 blocks
    const int z = logical >> 3, t = logical & 7;          // z 0..31
    const int bb = z >> 4, ii = z & 15;
    const int m0 = (t >> 2) * 128, n0 = (t & 3) * 256;
    const int K = K1 + ii * C;

    const ushort_t* hA = h + (long long)bb * T * F + (long long)(ii * C + m0) * F;
    const ushort_t* pA = P + (long long)bb * T * T + (long long)(ii * C + m0) * T;
    const ushort_t* wB = wdown + (long long)n0 * F;
    const ushort_t* tB = tpT + (long long)bb * D * T + (long long)n0 * T;

    ushort_t* A0s = smem2;              // 8192 ushorts each (16 KB)
    ushort_t* A1s = smem2 + 8192;
    ushort_t* B0s = smem2 + 16384;      // 16384 ushorts each (32 KB)
    ushort_t* B1s = smem2 + 32768;

    // hoisted loop-invariant fragment offsets
    int oa[2][2], ob[2][2];
#pragma unroll
    for (int m2 = 0; m2 < 2; ++m2)
#pragma unroll
        for (int k2 = 0; k2 < 2; ++k2)
            oa[m2][k2] = frag_off(wr * 64 + m2 * 32 + l32, k2 * 2 + hl);
#pragma unroll
    for (int n2 = 0; n2 < 2; ++n2)
#pragma unroll
        for (int k2 = 0; k2 < 2; ++k2)
            ob[n2][k2] = frag_off(wc * 64 + n2 * 32 + l32, k2 * 2 + hl);

    f32x16 acc[2][2];
#pragma unroll
    for (int a = 0; a < 2; ++a)
#pragma unroll
        for (int c = 0; c < 2; ++c) acc[a][c] = (f32x16)(0.f);

    auto srcA = [&](int kE) { return kE < K1 ? hA + kE : pA + (kE - K1); };
    auto srcB = [&](int kE) { return kE < K1 ? wB + kE : tB + (kE - K1); };

    const int NT = K >> 6;   // >= 64

    // prologue: A(0)h0,B(0)h0,A(0)h1,B(0)h1,A(1)h0,B(1)h0  (9 loads)
    stage_halfA(srcA(0), F, A0s, 0, tid);
    stage_half (srcB(0), F, 0, B0s, 0, tid);
    stage_halfA(srcA(0), F, A0s, 1, tid);
    stage_half (srcB(0), F, 0, B0s, 1, tid);
    stage_halfA(srcA(64), F, A1s, 0, tid);
    stage_half (srcB(64), F, 0, B1s, 0, tid);
    WAITV(6);
    BARRIER();

    for (int kt = 0; kt < NT; ++kt) {
        ushort_t* cA = (kt & 1) ? A1s : A0s;
        ushort_t* cB = (kt & 1) ? B1s : B0s;
        ushort_t* nA = (kt & 1) ? A0s : A1s;
        ushort_t* nB = (kt & 1) ? B0s : B1s;
        const bool h1 = (kt + 1 < NT), h2 = (kt + 2 < NT);
        const int kE1 = (kt + 1) << 6, kE2 = (kt + 2) << 6;
        bf16x8 af_[2][2], bf_[2][2];
        // ---- PH1: issue A(kt+1)h1 + B(kt+1)h1; read+MFMA ks 0-1; wait A/B(kt)h1
        if (h1) {
            stage_halfA(srcA(kE1), F, nA, 1, tid);
            stage_half (srcB(kE1), F, 0, nB, 1, tid);
        }
        oload_ks<0>(cA, cB, oa, ob, af_, bf_);
        __builtin_amdgcn_s_setprio(1);
        omfma(af_, bf_, acc);
        __builtin_amdgcn_s_setprio(0);
        if (h1) { WAITV(6); } else { WAITV(0); }
        BARRIER();
        // ---- PH2: issue A(kt+2)h0 + B(kt+2)h0; read+MFMA ks 2-3; wait A/B(kt+1)h0
        if (h2) {
            stage_halfA(srcA(kE2), F, cA, 0, tid);
            stage_half (srcB(kE2), F, 0, cB, 0, tid);
        }
        oload_ks<2>(cA, cB, oa, ob, af_, bf_);
        __builtin_amdgcn_s_setprio(1);
        omfma(af_, bf_, acc);
        __builtin_amdgcn_s_setprio(0);
        if (h2) { WAITV(6); } else { if (h1) { WAITV(3); } else { WAITV(0); } }
        BARRIER();
    }

    float* Op = out + (long long)bb * T * D + (long long)(ii * C) * D;
#pragma unroll
    for (int mi = 0; mi < 2; ++mi)
#pragma unroll
        for (int nj = 0; nj < 2; ++nj) {
            int col = n0 + wc * 64 + nj * 32 + l32;
#pragma unroll
            for (int reg = 0; reg < 16; ++reg) {
                int row = m0 + wr * 64 + mi * 32 + (reg & 3) + 8 * (reg >> 2) + 4 * hl;
                Op[(long long)row * D + col] = acc[mi][nj][reg];
            }
        }
}

// ---------- fused prep: fp32->bf16 converts (x|wgu|proj|wdown) + causal conv ----------
// permW: write wgu in the gate/up-interleaved row order for k_gemm256_silu.
// conv: 4 consecutive t-positions per thread (window reuse: tt read 1.6x not 5x).
__global__ void k_prep(const float* __restrict__ x, const float* __restrict__ wgu,
                       const float* __restrict__ proj, const float* __restrict__ wdown,
                       const float* __restrict__ tt, const float* __restrict__ cw,
                       const float* __restrict__ cb,
                       ushort_t* __restrict__ xb, ushort_t* __restrict__ gb,
                       ushort_t* __restrict__ pb, ushort_t* __restrict__ wb,
                       ushort_t* __restrict__ tb, int permW) {
    constexpr int T = 4096, D = 1024;
    int blk = blockIdx.x;
    if (blk < 21504) {
        // converts, float4-wide: x 2097152 | wgu 2097152 | proj 262144 | wdown 1048576 units
        int i = blk * 256 + threadIdx.x;
        const float* src; ushort_t* dst; int off; int dstoff;
        if (i < 2097152)      { src = x;     dst = xb; off = i; dstoff = off; }
        else if (i < 4194304) {
            src = wgu; dst = gb; off = i - 2097152;
            if (permW) {
                int r = off >> 8, cu = off & 255;
                int pr = (r < 4096) ? (((r >> 5) << 6) + (r & 31))
                                    : ((((r - 4096) >> 5) << 6) + 32 + ((r - 4096) & 31));
                dstoff = (pr << 8) + cu;
            } else dstoff = off;
        }
        else if (i < 4456448) { src = proj;  dst = pb; off = i - 4194304; dstoff = off; }
        else                  { src = wdown; dst = wb; off = i - 4456448; dstoff = off; }
        float4 v = ((const float4*)src)[off];
        ushort4 o; o.x = f2b(v.x); o.y = f2b(v.y); o.z = f2b(v.z); o.w = f2b(v.w);
        ((ushort4*)dst)[dstoff] = o;
    } else {
        // causal depthwise conv (K=5), 4 t-positions per thread, window reuse
        int idx = (blk - 21504) * 256 + threadIdx.x;      // B*(T/4)*D threads
        int d = idx & (D - 1);
        int tq = (idx >> 10) & (T / 4 - 1);
        int b = idx / (D * (T / 4));
        int t0 = tq * 4;
        const float* base = tt + (long long)b * T * D + d;
        float w0 = cw[d * 5 + 0], w1 = cw[d * 5 + 1], w2 = cw[d * 5 + 2],
              w3 = cw[d * 5 + 3], w4 = cw[d * 5 + 4];
        float bias = cb[d];
        float win[8];
#pragma unroll
        for (int m = 0; m < 8; ++m) {
            int ts = t0 - 4 + m;
            win[m] = (ts >= 0) ? base[(long long)ts * D] : 0.f;
        }
        ushort_t* op = tb + (long long)b * T * D + (long long)t0 * D + d;
#pragma unroll
        for (int r = 0; r < 4; ++r) {
            float a = bias + w0 * win[r] + w1 * win[r + 1] + w2 * win[r + 2]
                    + w3 * win[r + 3] + w4 * win[r + 4];
            op[(long long)r * D] = f2b(a);
        }
    }
}

// ---------- batched bf16 NT GEMM (bf16 out): C[m,n] = scale * sum_k A[m,k]*B[n,k] ----------
__global__ __launch_bounds__(256, 4)
void k_gemm_nt(const ushort_t* __restrict__ A, const ushort_t* __restrict__ B,
               ushort_t* __restrict__ C, int K, int lda, int ldb, int ldc,
               long long sAb, long long sBb, long long sCb, float scale) {
    __shared__ __attribute__((aligned(16))) ushort_t sA[BM * BK];
    __shared__ __attribute__((aligned(16))) ushort_t sB[BN * BK];

    int m0, n0;
    tile_decode(m0, n0);
    const int bb = blockIdx.z;
    const ushort_t* Ab = A + bb * sAb + (long long)m0 * lda;
    const ushort_t* Bb = B + bb * sBb + (long long)n0 * ldb;

    const int tid = threadIdx.x;
    const int lane = tid & 63, l32 = lane & 31, half = lane >> 5;
    const int wave = tid >> 6;
    const int wm = (wave >> 1) * 64, wn = (wave & 1) * 64;

    f32x16 acc[2][2];
#pragma unroll
    for (int i = 0; i < 2; ++i)
#pragma unroll
        for (int j = 0; j < 2; ++j) acc[i][j] = (f32x16)(0.f);

    for (int k0 = 0; k0 < K; k0 += BK) {
        __syncthreads();
        stage_tile(Ab, lda, k0, sA, tid);
        stage_tile(Bb, ldb, k0, sB, tid);
        __syncthreads();
#pragma unroll
        for (int ks = 0; ks < 4; ++ks) {
            bf16x8 af[2], bfr[2];
#pragma unroll
            for (int mi = 0; mi < 2; ++mi)
                af[mi] = ldfrag(sA, wm + mi * 32 + l32, ks * 2 + half);
#pragma unroll
            for (int nj = 0; nj < 2; ++nj)
                bfr[nj] = ldfrag(sB, wn + nj * 32 + l32, ks * 2 + half);
#pragma unroll
            for (int mi = 0; mi < 2; ++mi)
#pragma unroll
                for (int nj = 0; nj < 2; ++nj)
                    acc[mi][nj] = __builtin_amdgcn_mfma_f32_32x32x16_bf16(af[mi], bfr[nj], acc[mi][nj], 0, 0, 0);
        }
    }

    ushort_t* Cp = C + bb * sCb;
#pragma unroll
    for (int mi = 0; mi < 2; ++mi)
#pragma unroll
        for (int nj = 0; nj < 2; ++nj) {
            int col = n0 + wn + nj * 32 + l32;
#pragma unroll
            for (int reg = 0; reg < 16; ++reg) {
                int row = m0 + wm + mi * 32 + (reg & 3) + 8 * (reg >> 2) + 4 * half;
                Cp[(long long)row * ldc + col] = f2b(acc[mi][nj][reg] * scale);
            }
        }
}

// ---------- fallback fused gate_up GEMM + SiLU (unpermuted weights) ----------
__global__ __launch_bounds__(256)
void k_gemm_silu(const ushort_t* __restrict__ A, const ushort_t* __restrict__ Bg,
                 const ushort_t* __restrict__ Bu, ushort_t* __restrict__ H,
                 int K, int lda, int ldb, int ldh) {
    __shared__ __attribute__((aligned(16))) ushort_t sA[BM * BK];
    __shared__ __attribute__((aligned(16))) ushort_t sBg[BN * BK];
    __shared__ __attribute__((aligned(16))) ushort_t sBu[BN * BK];

    int m0, n0;
    tile_decode(m0, n0);
    const ushort_t* Ab = A + (long long)m0 * lda;
    const ushort_t* Bgb = Bg + (long long)n0 * ldb;
    const ushort_t* Bub = Bu + (long long)n0 * ldb;

    const int tid = threadIdx.x;
    const int lane = tid & 63, l32 = lane & 31, half = lane >> 5;
    const int wave = tid >> 6;
    const int wm = (wave >> 1) * 64, wn = (wave & 1) * 64;

    f32x16 ag[2][2], au[2][2];
#pragma unroll
    for (int i = 0; i < 2; ++i)
#pragma unroll
        for (int j = 0; j < 2; ++j) { ag[i][j] = (f32x16)(0.f); au[i][j] = (f32x16)(0.f); }

    for (int k0 = 0; k0 < K; k0 += BK) {
        __syncthreads();
        stage_tile(Ab, lda, k0, sA, tid);
        stage_tile(Bgb, ldb, k0, sBg, tid);
        stage_tile(Bub, ldb, k0, sBu, tid);
        __syncthreads();
#pragma unroll
        for (int ks = 0; ks < 4; ++ks) {
            bf16x8 af[2], bg[2], bu[2];
#pragma unroll
            for (int mi = 0; mi < 2; ++mi)
                af[mi] = ldfrag(sA, wm + mi * 32 + l32, ks * 2 + half);
#pragma unroll
            for (int nj = 0; nj < 2; ++nj) {
                bg[nj] = ldfrag(sBg, wn + nj * 32 + l32, ks * 2 + half);
                bu[nj] = ldfrag(sBu, wn + nj * 32 + l32, ks * 2 + half);
            }
#pragma unroll
            for (int mi = 0; mi < 2; ++mi)
#pragma unroll
                for (int nj = 0; nj < 2; ++nj) {
                    ag[mi][nj] = __builtin_amdgcn_mfma_f32_32x32x16_bf16(af[mi], bg[nj], ag[mi][nj], 0, 0, 0);
                    au[mi][nj] = __builtin_amdgcn_mfma_f32_32x32x16_bf16(af[mi], bu[nj], au[mi][nj], 0, 0, 0);
                }
        }
    }

#pragma unroll
    for (int mi = 0; mi < 2; ++mi)
#pragma unroll
        for (int nj = 0; nj < 2; ++nj) {
            int col = n0 + wn + nj * 32 + l32;
#pragma unroll
            for (int reg = 0; reg < 16; ++reg) {
                int row = m0 + wm + mi * 32 + (reg & 3) + 8 * (reg >> 2) + 4 * half;
                float g = ag[mi][nj][reg], u = au[mi][nj][reg];
                float s = g / (1.f + __expf(-g));
                H[(long long)row * ldh + col] = f2b(s * u);
            }
        }
}

// ---------- fallback triangular P GEMM (128^2 tiles) ----------
__global__ __launch_bounds__(256, 4)
void k_gemm_tri(const ushort_t* __restrict__ H, ushort_t* __restrict__ P,
                int K, int ldh, int ldp, long long sHb, long long sPb) {
    __shared__ __attribute__((aligned(16))) ushort_t sA[BM * BK];
    __shared__ __attribute__((aligned(16))) ushort_t sB[BN * BK];

    const int lin = blockIdx.x;
    const int g = lin >> 5, w = lin & 31;
    const int xk = w & 7, t = w >> 3;
    int pairIdx = g * 8 + xk;            // 0..239
    const int bb = pairIdx / 120;
    int p = pairIdx % 120;
    int i = 1, rem = p;
    while (rem >= i) { rem -= i; ++i; }
    const int j = rem;
    const int m0 = (t >> 1) * BM, n0 = (t & 1) * BN;

    const ushort_t* Ab = H + bb * sHb + (long long)(i * 256 + m0) * ldh;
    const ushort_t* Bb = H + bb * sHb + (long long)(j * 256 + n0) * ldh;

    const int tid = threadIdx.x;
    const int lane = tid & 63, l32 = lane & 31, half = lane >> 5;
    const int wave = tid >> 6;
    const int wm = (wave >> 1) * 64, wn = (wave & 1) * 64;

    f32x16 acc[2][2];
#pragma unroll
    for (int a = 0; a < 2; ++a)
#pragma unroll
        for (int c = 0; c < 2; ++c) acc[a][c] = (f32x16)(0.f);

    for (int k0 = 0; k0 < K; k0 += BK) {
        __syncthreads();
        stage_tile(Ab, ldh, k0, sA, tid);
        stage_tile(Bb, ldh, k0, sB, tid);
        __syncthreads();
#pragma unroll
        for (int ks = 0; ks < 4; ++ks) {
            bf16x8 af[2], bfr[2];
#pragma unroll
            for (int mi = 0; mi < 2; ++mi)
                af[mi] = ldfrag(sA, wm + mi * 32 + l32, ks * 2 + half);
#pragma unroll
            for (int nj = 0; nj < 2; ++nj)
                bfr[nj] = ldfrag(sB, wn + nj * 32 + l32, ks * 2 + half);
#pragma unroll
            for (int mi = 0; mi < 2; ++mi)
#pragma unroll
                for (int nj = 0; nj < 2; ++nj)
                    acc[mi][nj] = __builtin_amdgcn_mfma_f32_32x32x16_bf16(af[mi], bfr[nj], acc[mi][nj], 0, 0, 0);
        }
    }

    ushort_t* Pp = P + bb * sPb;
#pragma unroll
    for (int mi = 0; mi < 2; ++mi)
#pragma unroll
        for (int nj = 0; nj < 2; ++nj) {
            int col = j * 256 + n0 + wn + nj * 32 + l32;
#pragma unroll
            for (int reg = 0; reg < 16; ++reg) {
                int row = i * 256 + m0 + wm + mi * 32 + (reg & 3) + 8 * (reg >> 2) + 4 * half;
                Pp[(long long)row * ldp + col] = f2b(acc[mi][nj][reg]);
            }
        }
}

// ---------- fallback fused output GEMM (128^2) ----------
__global__ __launch_bounds__(256, 4)
void k_gemm_out(const ushort_t* __restrict__ h, const ushort_t* __restrict__ wdown,
                const ushort_t* __restrict__ P, const ushort_t* __restrict__ tpT,
                float* __restrict__ out) {
    constexpr int T = 4096, D = 1024, F = 4096, C = 256, K1 = 4096;
    __shared__ __attribute__((aligned(16))) ushort_t sA[BM * BK];
    __shared__ __attribute__((aligned(16))) ushort_t sB[BN * BK];

    const int z = blockIdx.z, bb = z >> 4, ii = z & 15;
    const int K2 = ii * C;
    int m0, n0;
    tile_decode(m0, n0);

    const ushort_t* A1 = h + (long long)bb * T * F + (long long)(ii * C + m0) * F;
    const ushort_t* B1 = wdown + (long long)n0 * F;
    const ushort_t* A2 = P + (long long)bb * T * T + (long long)(ii * C + m0) * T;
    const ushort_t* B2 = tpT + (long long)bb * D * T + (long long)n0 * T;

    const int tid = threadIdx.x;
    const int lane = tid & 63, l32 = lane & 31, half = lane >> 5;
    const int wave = tid >> 6;
    const int wm = (wave >> 1) * 64, wn = (wave & 1) * 64;

    f32x16 acc[2][2];
#pragma unroll
    for (int i = 0; i < 2; ++i)
#pragma unroll
        for (int j = 0; j < 2; ++j) acc[i][j] = (f32x16)(0.f);

    const int K = K1 + K2;
    for (int k0 = 0; k0 < K; k0 += BK) {
        const ushort_t* As = (k0 < K1) ? A1 + k0 : A2 + (k0 - K1);
        const ushort_t* Bs = (k0 < K1) ? B1 + k0 : B2 + (k0 - K1);
        __syncthreads();
        stage_tile(As, 4096, 0, sA, tid);
        stage_tile(Bs, 4096, 0, sB, tid);
        __syncthreads();
#pragma unroll
        for (int ks = 0; ks < 4; ++ks) {
            bf16x8 af[2], bfr[2];
#pragma unroll
            for (int mi = 0; mi < 2; ++mi)
                af[mi] = ldfrag(sA, wm + mi * 32 + l32, ks * 2 + half);
#pragma unroll
            for (int nj = 0; nj < 2; ++nj)
                bfr[nj] = ldfrag(sB, wn + nj * 32 + l32, ks * 2 + half);
#pragma unroll
            for (int mi = 0; mi < 2; ++mi)
#pragma unroll
                for (int nj = 0; nj < 2; ++nj)
                    acc[mi][nj] = __builtin_amdgcn_mfma_f32_32x32x16_bf16(af[mi], bfr[nj], acc[mi][nj], 0, 0, 0);
        }
    }

    float* Op = out + (long long)bb * T * D + (long long)ii * C * D;
#pragma unroll
    for (int mi = 0; mi < 2; ++mi)
#pragma unroll
        for (int nj = 0; nj < 2; ++nj) {
            int col = n0 + wn + nj * 32 + l32;
#pragma unroll
            for (int reg = 0; reg < 16; ++reg) {
                int row = m0 + wm + mi * 32 + (reg & 3) + 8 * (reg >> 2) + 4 * half;
                Op[(long long)row * D + col] = acc[mi][nj][reg];
            }
        }
}

// ---------- launch ----------
static int g_big = -1;

extern "C" void kernel_launch(void* const* d_in, const int* in_sizes, int n_in,
                              void* d_out, int out_size, void* d_ws, size_t ws_size,
                              hipStream_t stream) {
    const float* x         = (const float*)d_in[0];
    const float* ttt_tgt   = (const float*)d_in[1];
    const float* w_gate_up = (const float*)d_in[2];
    const float* w_down    = (const float*)d_in[3];
    const float* ttt_proj  = (const float*)d_in[4];
    const float* conv_w    = (const float*)d_in[5];
    const float* conv_b    = (const float*)d_in[6];
    float* out = (float*)d_out;
    (void)in_sizes; (void)n_in; (void)out_size; (void)ws_size;

    constexpr int Bb = 2, T = 4096, D = 1024, F = 4096, C = 256;
    constexpr float LR = 0.01f;

    // one-time: opt in to big dynamic LDS for the pipelined kernels; if the
    // runtime refuses, fall back to the 128^2 path (status-quo performance).
    if (g_big < 0) {
        hipError_t e1 = hipFuncSetAttribute((const void*)k_gemm256_silu,
                                            hipFuncAttributeMaxDynamicSharedMemorySize, 131072);
        hipError_t e2 = hipFuncSetAttribute((const void*)k_gemm256_tri,
                                            hipFuncAttributeMaxDynamicSharedMemorySize, 131072);
        hipError_t e3 = hipFuncSetAttribute((const void*)k_gemm256_out,
                                            hipFuncAttributeMaxDynamicSharedMemorySize, 98304);
        g_big = (e1 == hipSuccess && e2 == hipSuccess && e3 == hipSuccess) ? 1 : 0;
    }

    // workspace (154 MB):
    //   [0,64M): x_bf(16M) | wgu_bf(16M) | t_bf(16M) | scratch  -> later aliased by P (B,T,T) bf16
    //   [64M..): proj_bf 2M | wdown_bf 8M | tpT 16M | h 64M
    char* ws = (char*)d_ws;
    ushort_t* x_bf     = (ushort_t*)(ws);
    ushort_t* wgu_bf   = (ushort_t*)(ws + 16777216LL);
    ushort_t* t_bf     = (ushort_t*)(ws + 2 * 16777216LL);
    ushort_t* P        = (ushort_t*)(ws);
    ushort_t* proj_bf  = (ushort_t*)(ws + 67108864LL);
    ushort_t* wdown_bf = (ushort_t*)(ws + 67108864LL + 2097152LL);
    ushort_t* tpT      = (ushort_t*)(ws + 67108864LL + 2097152LL + 8388608LL);
    ushort_t* h        = (ushort_t*)(ws + 67108864LL + 2097152LL + 8388608LL + 16777216LL);

    // 1) fused prep: converts (+ optional gate/up row interleave) + causal conv
    //    conv 4 outputs/thread: 21504 cvt blocks + 8192 conv blocks
    k_prep<<<21504 + 8192, 256, 0, stream>>>(x, w_gate_up, ttt_proj, w_down,
                                             ttt_tgt, conv_w, conv_b,
                                             x_bf, wgu_bf, proj_bf, wdown_bf, t_bf, g_big);

    // 2) tpT[b] = LR * (proj @ t[b]^T) : M=D, N=T, K=D -> bf16 (B,D,T)
    k_gemm_nt<<<dim3(T / BN, D / BM, Bb), 256, 0, stream>>>(
        proj_bf, t_bf, tpT, D, D, D, T,
        0, (long long)T * D, (long long)D * T, LR);

    // 3) h = silu(x@Wg^T)*(x@Wu^T) : M=B*T=8192, N(permuted)=8192, K=1024
    if (g_big) {
        k_gemm256_silu<<<dim3(32, 32, 1), 512, 131072, stream>>>(x_bf, wgu_bf, h);
    } else {
        k_gemm_silu<<<dim3(F / BN, (Bb * T) / BM, 1), 256, 0, stream>>>(
            x_bf, wgu_bf, wgu_bf + (long long)F * D, h, D, D, D, F);
    }

    // 4) P lower chunk-blocks: P[b, i*C.., j*C..] = h_i h_j^T, j<i
    if (g_big) {
        k_gemm256_tri<<<dim3(240, 1, 1), 512, 131072, stream>>>(h, P);
    } else {
        k_gemm_tri<<<dim3(960, 1, 1), 256, 0, stream>>>(
            h, P, F, F, T, (long long)T * F, (long long)T * T);
    }

    // 5) out[b,i] = [h_i | P] @ [wdown | LR*tpT]^T  (variable K = 4096 + i*256)
    if (g_big) {
        k_gemm256_out<<<dim3(256, 1, 1), 512, 98304, stream>>>(h, wdown_bf, P, tpT, out);
    } else {
        k_gemm_out<<<dim3(D / BN, C / BM, Bb * 16), 256, 0, stream>>>(
            h, wdown_bf, P, tpT, out);
    }
}